// Round 9
// baseline (355.115 us; speedup 1.0000x reference)
//
#include <hip/hip_runtime.h>
#include <math.h>

#define N_NODES 100000
#define N_EDGES 1600000
#define NB 391              // dst buckets (d>>8), 256 nodes each
#define MROWS 100096        // 782*128, padded row count for guard-free tiles
#define CH 3200             // edges per bucket_scatter block -> 500 blocks

typedef __attribute__((ext_vector_type(8))) short short8;  // 8 bf16 = 4 VGPRs
typedef __attribute__((ext_vector_type(4))) float f32x4;
typedef __attribute__((ext_vector_type(2))) float f32x2;

__device__ __forceinline__ short f2b(float f) {            // fp32 -> bf16 RNE
    unsigned u = __float_as_uint(f);
    unsigned r = (u + 0x7FFFu + ((u >> 16) & 1u)) >> 16;
    return (short)r;
}
__device__ __forceinline__ float b2f(short s) {
    return __uint_as_float(((unsigned)(unsigned short)s) << 16);
}
__device__ __forceinline__ unsigned pk2(float a, float b) {
    return (unsigned)(unsigned short)f2b(a) | ((unsigned)(unsigned short)f2b(b) << 16);
}
// f32 -> fp8 e4m3 (OCP), single byte
__device__ __forceinline__ unsigned char f2q(float v) {
    return (unsigned char)(__builtin_amdgcn_cvt_pk_fp8_f32(v, 0.f, 0, false) & 0xFF);
}
// accumulate 4 fp8 (one uint) into a[0..3]
__device__ __forceinline__ void acc4(float* a, unsigned u) {
    f32x2 lo = __builtin_amdgcn_cvt_pk_f32_fp8((int)u, false);
    f32x2 hi = __builtin_amdgcn_cvt_pk_f32_fp8((int)u, true);
    a[0] += lo[0]; a[1] += lo[1]; a[2] += hi[0]; a[3] += hi[1];
}
__device__ __forceinline__ void acc16(float* a, uint4 u) {
    acc4(a + 0, u.x); acc4(a + 4, u.y); acc4(a + 8, u.z); acc4(a + 12, u.w);
}

// pack 8 fp32 -> 8 bf16 (RNE)
__device__ __forceinline__ short8 pack8(const float* __restrict__ p) {
    float4 v0 = ((const float4*)p)[0];
    float4 v1 = ((const float4*)p)[1];
    short8 h;
    h[0] = f2b(v0.x); h[1] = f2b(v0.y); h[2] = f2b(v0.z); h[3] = f2b(v0.w);
    h[4] = f2b(v1.x); h[5] = f2b(v1.y); h[6] = f2b(v1.z); h[7] = f2b(v1.w);
    return h;
}

// ---------- bucket histogram (LDS-staged) ----------
__global__ __launch_bounds__(256) void bucket_count(const int* __restrict__ dst,
                                                    int* __restrict__ bcnt) {
    __shared__ int h[NB];
    int t = threadIdx.x;
    for (int i = t; i < NB; i += 256) h[i] = 0;
    __syncthreads();
    for (int e = blockIdx.x * 256 + t; e < N_EDGES; e += gridDim.x * 256)
        atomicAdd(&h[dst[e] >> 8], 1);
    __syncthreads();
    for (int i = t; i < NB; i += 256)
        if (h[i]) atomicAdd(&bcnt[i], h[i]);
}

// ---------- bucket-level exclusive scan (one block) ----------
__global__ __launch_bounds__(512) void bucket_scan(const int* __restrict__ bcnt,
                                                   int* __restrict__ boffs,
                                                   int* __restrict__ bcur) {
    __shared__ int s[512];
    int t = threadIdx.x;
    int v = (t < NB) ? bcnt[t] : 0;
    s[t] = v;
    __syncthreads();
    for (int off = 1; off < 512; off <<= 1) {
        int u = (t >= off) ? s[t - off] : 0;
        __syncthreads();
        s[t] += u;
        __syncthreads();
    }
    if (t < NB) {
        int ex = s[t] - v;
        boffs[t] = ex;
        bcur[t] = ex;
    }
    if (t == 0) boffs[NB] = N_EDGES;
}

// ---------- scatter edges into bucket-grouped packed list ----------
// packed word: (d&255)<<24 | src   (src < 2^24)
__global__ __launch_bounds__(256) void bucket_scatter(const int* __restrict__ src,
                                                      const int* __restrict__ dst,
                                                      int* __restrict__ bcur,
                                                      unsigned* __restrict__ pairs) {
    __shared__ unsigned lw[CH];
    __shared__ short lb[CH];
    __shared__ int cnt[NB];
    __shared__ int lstart[NB];
    int t = threadIdx.x;
    int e0 = blockIdx.x * CH;
    int n = min(CH, N_EDGES - e0);
    for (int i = t; i < NB; i += 256) cnt[i] = 0;
    __syncthreads();
    for (int i = t; i < n; i += 256) {
        int s = src[e0 + i], d = dst[e0 + i];
        lw[i] = ((unsigned)(d & 255) << 24) | (unsigned)s;
        int b = d >> 8;
        lb[i] = (short)b;
        atomicAdd(&cnt[b], 1);
    }
    __syncthreads();
    for (int b = t; b < NB; b += 256) {
        int c = cnt[b];
        lstart[b] = c ? atomicAdd(&bcur[b], c) : 0;
        cnt[b] = 0;  // reuse as local cursor
    }
    __syncthreads();
    for (int i = t; i < n; i += 256) {
        int b = lb[i];
        int lo = atomicAdd(&cnt[b], 1);
        pairs[lstart[b] + lo] = lw[i];
    }
}

// ---------- bucket-local CSR fill; derives rowp + dinv in-kernel ----------
__global__ __launch_bounds__(256) void csr_fill_bucket(const unsigned* __restrict__ pairs,
                                                       const int* __restrict__ boffs,
                                                       int* __restrict__ rowp,
                                                       float* __restrict__ dinv,
                                                       int* __restrict__ srcs) {
    __shared__ int lcnt[256];
    __shared__ int ls[256];
    int t = threadIdx.x;
    int b = blockIdx.x;
    int base = b << 8;
    lcnt[t] = 0;
    __syncthreads();
    int lo_e = boffs[b], hi_e = boffs[b + 1];
    for (int i = lo_e + t; i < hi_e; i += 256)
        atomicAdd(&lcnt[pairs[i] >> 24], 1);
    __syncthreads();
    int c = lcnt[t];
    ls[t] = c;
    __syncthreads();
    for (int off = 1; off < 256; off <<= 1) {
        int u = (t >= off) ? ls[t - off] : 0;
        __syncthreads();
        ls[t] += u;
        __syncthreads();
    }
    int rp = lo_e + ls[t] - c;
    int node = base + t;
    if (node < N_NODES) {
        rowp[node] = rp;
        dinv[node] = rsqrtf((float)(c + 1));
    }
    if (b == 0 && t == 0) rowp[N_NODES] = N_EDGES;
    __syncthreads();
    lcnt[t] = rp;  // reuse as global cursor
    __syncthreads();
    for (int i = lo_e + t; i < hi_e; i += 256) {
        unsigned p = pairs[i];
        int li = p >> 24;
        int pos = atomicAdd(&lcnt[li], 1);
        srcs[pos] = (int)(p & 0xFFFFFFu);
    }
}

// ---------- W1 [128][128] + W2 [128][64] fp32 -> Wt [N][128] split bf16 ----------
__global__ __launch_bounds__(256) void convert_w(const float* __restrict__ W1,
                                                 const float* __restrict__ W2,
                                                 short* __restrict__ w1hi,
                                                 short* __restrict__ w1lo,
                                                 short* __restrict__ w2hi,
                                                 short* __restrict__ w2lo) {
    int id = blockIdx.x * 256 + threadIdx.x;
    if (id < 128 * 128) {
        int n = id >> 7, k = id & 127;
        float v = W1[k * 128 + n];
        short h = f2b(v);
        w1hi[id] = h;
        w1lo[id] = f2b(v - b2f(h));
    } else if (id < 128 * 128 + 64 * 128) {
        int j = id - 128 * 128;
        int n = j >> 7, k = j & 127;
        float v = W2[k * 64 + n];
        short h = f2b(v);
        w2hi[j] = h;
        w2lo[j] = f2b(v - b2f(h));
    }
}

// ---------- layer-1 GEMM: Y1 = fp8((X @ W1) * dinv); A=bf16(X), B split ----------
__global__ __launch_bounds__(256) void gemm1_mfma(const float* __restrict__ X,
                                                  const short* __restrict__ Wthi,
                                                  const short* __restrict__ Wtlo,
                                                  const float* __restrict__ dinv,
                                                  unsigned char* __restrict__ Yf) {
    const int t = threadIdx.x;
    const int w = t >> 6, lane = t & 63;
    const int m = lane & 15, q = lane >> 4;
    const int r0 = blockIdx.x * 128 + w * 32;
    const int ra = min(r0 + m, N_NODES - 1);
    const int rb = min(r0 + 16 + m, N_NODES - 1);

    f32x4 acc[2][8];
#pragma unroll
    for (int i = 0; i < 2; ++i)
#pragma unroll
        for (int c = 0; c < 8; ++c) acc[i][c] = (f32x4)(0.f);

#pragma unroll
    for (int kk = 0; kk < 4; ++kk) {
        const int koff = kk * 32 + q * 8;
        short8 ah0 = pack8(X + (size_t)ra * 128 + koff);
        short8 ah1 = pack8(X + (size_t)rb * 128 + koff);
#pragma unroll
        for (int c = 0; c < 8; ++c) {
            short8 bh = *(const short8*)(Wthi + (c * 16 + m) * 128 + koff);
            short8 bl = *(const short8*)(Wtlo + (c * 16 + m) * 128 + koff);
            acc[0][c] = __builtin_amdgcn_mfma_f32_16x16x32_bf16(ah0, bh, acc[0][c], 0, 0, 0);
            acc[1][c] = __builtin_amdgcn_mfma_f32_16x16x32_bf16(ah1, bh, acc[1][c], 0, 0, 0);
            acc[0][c] = __builtin_amdgcn_mfma_f32_16x16x32_bf16(ah0, bl, acc[0][c], 0, 0, 0);
            acc[1][c] = __builtin_amdgcn_mfma_f32_16x16x32_bf16(ah1, bl, acc[1][c], 0, 0, 0);
        }
    }

    const int rb0 = r0 + q * 4;
    const int rb1 = r0 + 16 + q * 4;
    f32x4 dv0 = *(const f32x4*)(dinv + rb0);
    f32x4 dv1 = *(const f32x4*)(dinv + rb1);
#pragma unroll
    for (int c = 0; c < 8; ++c) {
        const int col = c * 16 + m;
#pragma unroll
        for (int r = 0; r < 4; ++r) {
            int row = rb0 + r;
            if (row < N_NODES) Yf[(size_t)row * 128 + col] = f2q(acc[0][c][r] * dv0[r]);
            row = rb1 + r;
            if (row < N_NODES) Yf[(size_t)row * 128 + col] = f2q(acc[1][c][r] * dv1[r]);
        }
    }
}

// ---------- layer-2 GEMM: Y2 = fp8((H @ W2) * dinv), H plain bf16 ----------
__global__ __launch_bounds__(256) void gemm2_mfma(const short* __restrict__ H,
                                                  const short* __restrict__ Wthi,
                                                  const short* __restrict__ Wtlo,
                                                  const float* __restrict__ dinv,
                                                  unsigned char* __restrict__ Yf) {
    const int t = threadIdx.x;
    const int w = t >> 6, lane = t & 63;
    const int m = lane & 15, q = lane >> 4;
    const int r0 = blockIdx.x * 128 + w * 32;

    f32x4 acc[2][4];
#pragma unroll
    for (int i = 0; i < 2; ++i)
#pragma unroll
        for (int c = 0; c < 4; ++c) acc[i][c] = (f32x4)(0.f);

#pragma unroll
    for (int kk = 0; kk < 4; ++kk) {
        const int koff = kk * 32 + q * 8;
        short8 ah0 = *(const short8*)(H + (size_t)(r0 + m) * 128 + koff);
        short8 ah1 = *(const short8*)(H + (size_t)(r0 + 16 + m) * 128 + koff);
#pragma unroll
        for (int c = 0; c < 4; ++c) {
            short8 bh = *(const short8*)(Wthi + (c * 16 + m) * 128 + koff);
            short8 bl = *(const short8*)(Wtlo + (c * 16 + m) * 128 + koff);
            acc[0][c] = __builtin_amdgcn_mfma_f32_16x16x32_bf16(ah0, bh, acc[0][c], 0, 0, 0);
            acc[1][c] = __builtin_amdgcn_mfma_f32_16x16x32_bf16(ah1, bh, acc[1][c], 0, 0, 0);
            acc[0][c] = __builtin_amdgcn_mfma_f32_16x16x32_bf16(ah0, bl, acc[0][c], 0, 0, 0);
            acc[1][c] = __builtin_amdgcn_mfma_f32_16x16x32_bf16(ah1, bl, acc[1][c], 0, 0, 0);
        }
    }

    const int rb0 = r0 + q * 4;
    const int rb1 = r0 + 16 + q * 4;
    f32x4 dv0 = *(const f32x4*)(dinv + rb0);
    f32x4 dv1 = *(const f32x4*)(dinv + rb1);
#pragma unroll
    for (int c = 0; c < 4; ++c) {
        const int col = c * 16 + m;
#pragma unroll
        for (int r = 0; r < 4; ++r) {
            int row = rb0 + r;
            if (row < N_NODES) Yf[(size_t)row * 64 + col] = f2q(acc[0][c][r] * dv0[r]);
            row = rb1 + r;
            if (row < N_NODES) Yf[(size_t)row * 64 + col] = f2q(acc[1][c][r] * dv1[r]);
        }
    }
}

// ---------- CSR aggregation, K=128 fp8 in: eighth-wave/edge, f32 acc, bf16 out ----------
__global__ __launch_bounds__(256) void agg_relu(const int* __restrict__ rowp,
                                                const int* __restrict__ srcs,
                                                const unsigned char* __restrict__ Yf,
                                                const float* __restrict__ dinv,
                                                const float* __restrict__ b,
                                                short* __restrict__ Hb) {
    int t = threadIdx.x;
    int lane = t & 63, w = t >> 6;
    int gi = lane >> 3, li = lane & 7;        // 8 groups of 8 lanes
    int d = blockIdx.x * 4 + w;
    if (d >= N_NODES) return;
    const uint4* Y8 = (const uint4*)Yf;       // row = 8 uint4 (128 fp8)
    float a[16];
#pragma unroll
    for (int i = 0; i < 16; ++i) a[i] = 0.f;
    if (gi == 0) {                             // self loop into group 0
        uint4 u = Y8[(size_t)d * 8 + li];
        acc16(a, u);
    }
    int e = rowp[d], end = rowp[d + 1];
    for (; e + 16 <= end; e += 16) {           // 16 edges/iter, 2 loads in flight
        int s0 = srcs[e + gi], s1 = srcs[e + 8 + gi];
        uint4 u0 = Y8[(size_t)s0 * 8 + li];
        uint4 u1 = Y8[(size_t)s1 * 8 + li];
        acc16(a, u0);
        acc16(a, u1);
    }
    for (; e < end; e += 8) {                  // masked remainder, 8 edges/step
        int idx = e + gi;
        int s = srcs[(idx < end) ? idx : e];
        uint4 u = Y8[(size_t)s * 8 + li];
        if (idx < end) acc16(a, u);
    }
#pragma unroll
    for (int i = 0; i < 16; ++i) {
        a[i] += __shfl_xor(a[i], 8);
        a[i] += __shfl_xor(a[i], 16);
        a[i] += __shfl_xor(a[i], 32);
    }
    if (gi == 0) {                             // feats 16*li .. 16*li+15
        float sc = dinv[d];
        const float4* B4 = (const float4*)b;
        float v[16];
#pragma unroll
        for (int j = 0; j < 4; ++j) {
            float4 bb = B4[4 * li + j];
            v[4 * j + 0] = fmaxf(sc * a[4 * j + 0] + bb.x, 0.f);
            v[4 * j + 1] = fmaxf(sc * a[4 * j + 1] + bb.y, 0.f);
            v[4 * j + 2] = fmaxf(sc * a[4 * j + 2] + bb.z, 0.f);
            v[4 * j + 3] = fmaxf(sc * a[4 * j + 3] + bb.w, 0.f);
        }
        uint4 o0 = make_uint4(pk2(v[0], v[1]), pk2(v[2], v[3]),
                              pk2(v[4], v[5]), pk2(v[6], v[7]));
        uint4 o1 = make_uint4(pk2(v[8], v[9]), pk2(v[10], v[11]),
                              pk2(v[12], v[13]), pk2(v[14], v[15]));
        ((uint4*)Hb)[(size_t)d * 16 + 2 * li] = o0;
        ((uint4*)Hb)[(size_t)d * 16 + 2 * li + 1] = o1;
    }
}

// ---------- CSR aggregation, K=64 fp8 in: sixteenth-wave/edge + log_softmax ----------
__global__ __launch_bounds__(256) void agg_lsm(const int* __restrict__ rowp,
                                               const int* __restrict__ srcs,
                                               const unsigned char* __restrict__ Yf,
                                               const float* __restrict__ dinv,
                                               const float* __restrict__ b,
                                               float* __restrict__ out) {
    int t = threadIdx.x;
    int lane = t & 63, w = t >> 6;
    int gi = lane >> 2, li = lane & 3;        // 16 groups of 4 lanes
    int d = blockIdx.x * 4 + w;
    if (d >= N_NODES) return;
    const uint4* Y4 = (const uint4*)Yf;       // row = 4 uint4 (64 fp8)
    float a[16];
#pragma unroll
    for (int i = 0; i < 16; ++i) a[i] = 0.f;
    if (gi == 0) {                             // self loop
        uint4 u = Y4[(size_t)d * 4 + li];
        acc16(a, u);
    }
    int e = rowp[d], end = rowp[d + 1];
    for (; e + 32 <= end; e += 32) {           // 32 edges/iter
        int s0 = srcs[e + gi], s1 = srcs[e + 16 + gi];
        uint4 u0 = Y4[(size_t)s0 * 4 + li];
        uint4 u1 = Y4[(size_t)s1 * 4 + li];
        acc16(a, u0);
        acc16(a, u1);
    }
    for (; e < end; e += 16) {                 // masked remainder, 16 edges/step
        int idx = e + gi;
        int s = srcs[(idx < end) ? idx : e];
        uint4 u = Y4[(size_t)s * 4 + li];
        if (idx < end) acc16(a, u);
    }
#pragma unroll
    for (int i = 0; i < 16; ++i) {
        a[i] += __shfl_xor(a[i], 4);
        a[i] += __shfl_xor(a[i], 8);
        a[i] += __shfl_xor(a[i], 16);
        a[i] += __shfl_xor(a[i], 32);
    }
    // lane li holds feats 16*li .. 16*li+15 (same in every group)
    float sc = dinv[d];
    const float4* B4 = (const float4*)b;
    float v[16];
#pragma unroll
    for (int j = 0; j < 4; ++j) {
        float4 bb = B4[4 * li + j];
        v[4 * j + 0] = sc * a[4 * j + 0] + bb.x;
        v[4 * j + 1] = sc * a[4 * j + 1] + bb.y;
        v[4 * j + 2] = sc * a[4 * j + 2] + bb.z;
        v[4 * j + 3] = sc * a[4 * j + 3] + bb.w;
    }
    float m = v[0];
#pragma unroll
    for (int i = 1; i < 16; ++i) m = fmaxf(m, v[i]);
    m = fmaxf(m, __shfl_xor(m, 1));
    m = fmaxf(m, __shfl_xor(m, 2));
    float su = 0.f;
#pragma unroll
    for (int i = 0; i < 16; ++i) su += __expf(v[i] - m);
    su += __shfl_xor(su, 1);
    su += __shfl_xor(su, 2);
    float ls = m + logf(su);
    if (gi == 0) {
#pragma unroll
        for (int j = 0; j < 4; ++j)
            ((float4*)out)[(size_t)d * 16 + 4 * li + j] =
                make_float4(v[4 * j] - ls, v[4 * j + 1] - ls,
                            v[4 * j + 2] - ls, v[4 * j + 3] - ls);
    }
}

extern "C" void kernel_launch(void* const* d_in, const int* in_sizes, int n_in,
                              void* d_out, int out_size, void* d_ws, size_t ws_size,
                              hipStream_t stream) {
    const float* x  = (const float*)d_in[0];
    const float* W1 = (const float*)d_in[1];
    const float* b1 = (const float*)d_in[2];
    const float* W2 = (const float*)d_in[3];
    const float* b2 = (const float*)d_in[4];
    const int* edge = (const int*)d_in[5];
    const int* src = edge;
    const int* dst = edge + N_EDGES;
    float* out = (float*)d_out;

    char* ws = (char*)d_ws;
    int*           bcnt  = (int*)(ws + 0);            //     1,564
    int*           boffs = (int*)(ws + 2048);         //     1,568
    int*           bcur  = (int*)(ws + 4096);         //     1,564
    float*         dinv  = (float*)(ws + 6144);       //   400,384 (MROWS)
    int*           rowp  = (int*)(ws + 406528);       //   400,008
    int*           srcs  = (int*)(ws + 806912);       // 6,400,000
    unsigned*      pairs = (unsigned*)(ws + 7206912); // 6,400,000
    short*         w1hi  = (short*)(ws + 13606912);   //    32,768
    short*         w1lo  = (short*)(ws + 13639680);   //    32,768
    short*         w2hi  = (short*)(ws + 13672448);   //    16,384
    short*         w2lo  = (short*)(ws + 13688832);   //    16,384
    unsigned char* y1f   = (unsigned char*)(ws + 13705216); // 12,812,288 (MROWS*128 fp8)
    short*         h1b   = (short*)(ws + 26517504);   // 25,624,576 (MROWS*128 bf16)
    unsigned char* y2f   = (unsigned char*)(ws + 52142080); //  6,406,144 (MROWS*64 fp8)
    // ends ~58.5 MB

    // ---- CSR build: bucket histogram -> scan -> scatter -> bucket-local fill ----
    hipMemsetAsync(bcnt, 0, NB * sizeof(int), stream);
    bucket_count<<<512, 256, 0, stream>>>(dst, bcnt);
    bucket_scan<<<1, 512, 0, stream>>>(bcnt, boffs, bcur);
    bucket_scatter<<<(N_EDGES + CH - 1) / CH, 256, 0, stream>>>(src, dst, bcur, pairs);
    csr_fill_bucket<<<NB, 256, 0, stream>>>(pairs, boffs, rowp, dinv, srcs);

    // ---- weight conversion ----
    convert_w<<<(128 * 128 + 64 * 128 + 255) / 256, 256, 0, stream>>>(W1, W2, w1hi, w1lo,
                                                                      w2hi, w2lo);

    // ---- layer 1 ----
    gemm1_mfma<<<MROWS / 128, 256, 0, stream>>>(x, w1hi, w1lo, dinv, y1f);
    agg_relu<<<(N_NODES + 3) / 4, 256, 0, stream>>>(rowp, srcs, y1f, dinv, b1, h1b);

    // ---- layer 2 ----
    gemm2_mfma<<<MROWS / 128, 256, 0, stream>>>(h1b, w2hi, w2lo, dinv, y2f);
    agg_lsm<<<(N_NODES + 3) / 4, 256, 0, stream>>>(rowp, srcs, y2f, dinv, b2, out);
}

// Round 10
// 333.832 us; speedup vs baseline: 1.0638x; 1.0638x over previous
//
#include <hip/hip_runtime.h>
#include <math.h>

#define N_NODES 100000
#define N_EDGES 1600000
#define NB 391              // dst buckets (d>>8), 256 nodes each
#define MROWS 100096        // 782*128, padded row count for guard-free tiles
#define CH 3200             // edges per bucket_scatter block -> 500 blocks

typedef __attribute__((ext_vector_type(8))) short short8;  // 8 bf16 = 4 VGPRs
typedef __attribute__((ext_vector_type(4))) float f32x4;
typedef __attribute__((ext_vector_type(2))) float f32x2;

__device__ __forceinline__ short f2b(float f) {            // fp32 -> bf16 RNE
    unsigned u = __float_as_uint(f);
    unsigned r = (u + 0x7FFFu + ((u >> 16) & 1u)) >> 16;
    return (short)r;
}
__device__ __forceinline__ float b2f(short s) {
    return __uint_as_float(((unsigned)(unsigned short)s) << 16);
}
__device__ __forceinline__ unsigned pk2(float a, float b) {
    return (unsigned)(unsigned short)f2b(a) | ((unsigned)(unsigned short)f2b(b) << 16);
}
// f32 -> fp8 e4m3 (OCP), single byte
__device__ __forceinline__ unsigned char f2q(float v) {
    return (unsigned char)(__builtin_amdgcn_cvt_pk_fp8_f32(v, 0.f, 0, false) & 0xFF);
}
// accumulate 4 fp8 (one uint) into a[0..3]
__device__ __forceinline__ void acc4(float* a, unsigned u) {
    f32x2 lo = __builtin_amdgcn_cvt_pk_f32_fp8((int)u, false);
    f32x2 hi = __builtin_amdgcn_cvt_pk_f32_fp8((int)u, true);
    a[0] += lo[0]; a[1] += lo[1]; a[2] += hi[0]; a[3] += hi[1];
}

// pack 8 fp32 -> 8 bf16 (RNE)
__device__ __forceinline__ short8 pack8(const float* __restrict__ p) {
    float4 v0 = ((const float4*)p)[0];
    float4 v1 = ((const float4*)p)[1];
    short8 h;
    h[0] = f2b(v0.x); h[1] = f2b(v0.y); h[2] = f2b(v0.z); h[3] = f2b(v0.w);
    h[4] = f2b(v1.x); h[5] = f2b(v1.y); h[6] = f2b(v1.z); h[7] = f2b(v1.w);
    return h;
}

// ---------- bucket histogram (LDS-staged) ----------
__global__ __launch_bounds__(256) void bucket_count(const int* __restrict__ dst,
                                                    int* __restrict__ bcnt) {
    __shared__ int h[NB];
    int t = threadIdx.x;
    for (int i = t; i < NB; i += 256) h[i] = 0;
    __syncthreads();
    for (int e = blockIdx.x * 256 + t; e < N_EDGES; e += gridDim.x * 256)
        atomicAdd(&h[dst[e] >> 8], 1);
    __syncthreads();
    for (int i = t; i < NB; i += 256)
        if (h[i]) atomicAdd(&bcnt[i], h[i]);
}

// ---------- bucket-level exclusive scan (one block) ----------
__global__ __launch_bounds__(512) void bucket_scan(const int* __restrict__ bcnt,
                                                   int* __restrict__ boffs,
                                                   int* __restrict__ bcur) {
    __shared__ int s[512];
    int t = threadIdx.x;
    int v = (t < NB) ? bcnt[t] : 0;
    s[t] = v;
    __syncthreads();
    for (int off = 1; off < 512; off <<= 1) {
        int u = (t >= off) ? s[t - off] : 0;
        __syncthreads();
        s[t] += u;
        __syncthreads();
    }
    if (t < NB) {
        int ex = s[t] - v;
        boffs[t] = ex;
        bcur[t] = ex;
    }
    if (t == 0) boffs[NB] = N_EDGES;
}

// ---------- scatter edges into bucket-grouped packed list ----------
// packed word: (d&255)<<24 | src   (src < 2^24)
__global__ __launch_bounds__(256) void bucket_scatter(const int* __restrict__ src,
                                                      const int* __restrict__ dst,
                                                      int* __restrict__ bcur,
                                                      unsigned* __restrict__ pairs) {
    __shared__ unsigned lw[CH];
    __shared__ short lb[CH];
    __shared__ int cnt[NB];
    __shared__ int lstart[NB];
    int t = threadIdx.x;
    int e0 = blockIdx.x * CH;
    int n = min(CH, N_EDGES - e0);
    for (int i = t; i < NB; i += 256) cnt[i] = 0;
    __syncthreads();
    for (int i = t; i < n; i += 256) {
        int s = src[e0 + i], d = dst[e0 + i];
        lw[i] = ((unsigned)(d & 255) << 24) | (unsigned)s;
        int b = d >> 8;
        lb[i] = (short)b;
        atomicAdd(&cnt[b], 1);
    }
    __syncthreads();
    for (int b = t; b < NB; b += 256) {
        int c = cnt[b];
        lstart[b] = c ? atomicAdd(&bcur[b], c) : 0;
        cnt[b] = 0;  // reuse as local cursor
    }
    __syncthreads();
    for (int i = t; i < n; i += 256) {
        int b = lb[i];
        int lo = atomicAdd(&cnt[b], 1);
        pairs[lstart[b] + lo] = lw[i];
    }
}

// ---------- bucket-local CSR fill; derives rowp + dinv in-kernel ----------
__global__ __launch_bounds__(256) void csr_fill_bucket(const unsigned* __restrict__ pairs,
                                                       const int* __restrict__ boffs,
                                                       int* __restrict__ rowp,
                                                       float* __restrict__ dinv,
                                                       int* __restrict__ srcs) {
    __shared__ int lcnt[256];
    __shared__ int ls[256];
    int t = threadIdx.x;
    int b = blockIdx.x;
    int base = b << 8;
    lcnt[t] = 0;
    __syncthreads();
    int lo_e = boffs[b], hi_e = boffs[b + 1];
    for (int i = lo_e + t; i < hi_e; i += 256)
        atomicAdd(&lcnt[pairs[i] >> 24], 1);
    __syncthreads();
    int c = lcnt[t];
    ls[t] = c;
    __syncthreads();
    for (int off = 1; off < 256; off <<= 1) {
        int u = (t >= off) ? ls[t - off] : 0;
        __syncthreads();
        ls[t] += u;
        __syncthreads();
    }
    int rp = lo_e + ls[t] - c;
    int node = base + t;
    if (node < N_NODES) {
        rowp[node] = rp;
        dinv[node] = rsqrtf((float)(c + 1));
    }
    if (b == 0 && t == 0) rowp[N_NODES] = N_EDGES;
    __syncthreads();
    lcnt[t] = rp;  // reuse as global cursor
    __syncthreads();
    for (int i = lo_e + t; i < hi_e; i += 256) {
        unsigned p = pairs[i];
        int li = p >> 24;
        int pos = atomicAdd(&lcnt[li], 1);
        srcs[pos] = (int)(p & 0xFFFFFFu);
    }
}

// ---------- W1 [128][128] + W2 [128][64] fp32 -> Wt [N][128] split bf16 ----------
__global__ __launch_bounds__(256) void convert_w(const float* __restrict__ W1,
                                                 const float* __restrict__ W2,
                                                 short* __restrict__ w1hi,
                                                 short* __restrict__ w1lo,
                                                 short* __restrict__ w2hi,
                                                 short* __restrict__ w2lo) {
    int id = blockIdx.x * 256 + threadIdx.x;
    if (id < 128 * 128) {
        int n = id >> 7, k = id & 127;
        float v = W1[k * 128 + n];
        short h = f2b(v);
        w1hi[id] = h;
        w1lo[id] = f2b(v - b2f(h));
    } else if (id < 128 * 128 + 64 * 128) {
        int j = id - 128 * 128;
        int n = j >> 7, k = j & 127;
        float v = W2[k * 64 + n];
        short h = f2b(v);
        w2hi[j] = h;
        w2lo[j] = f2b(v - b2f(h));
    }
}

// ---------- layer-1 GEMM: Y1 = fp8((X @ W1) * dinv); A=bf16(X), B split ----------
__global__ __launch_bounds__(256) void gemm1_mfma(const float* __restrict__ X,
                                                  const short* __restrict__ Wthi,
                                                  const short* __restrict__ Wtlo,
                                                  const float* __restrict__ dinv,
                                                  unsigned char* __restrict__ Yf) {
    const int t = threadIdx.x;
    const int w = t >> 6, lane = t & 63;
    const int m = lane & 15, q = lane >> 4;
    const int r0 = blockIdx.x * 128 + w * 32;
    const int ra = min(r0 + m, N_NODES - 1);
    const int rb = min(r0 + 16 + m, N_NODES - 1);

    f32x4 acc[2][8];
#pragma unroll
    for (int i = 0; i < 2; ++i)
#pragma unroll
        for (int c = 0; c < 8; ++c) acc[i][c] = (f32x4)(0.f);

#pragma unroll
    for (int kk = 0; kk < 4; ++kk) {
        const int koff = kk * 32 + q * 8;
        short8 ah0 = pack8(X + (size_t)ra * 128 + koff);
        short8 ah1 = pack8(X + (size_t)rb * 128 + koff);
#pragma unroll
        for (int c = 0; c < 8; ++c) {
            short8 bh = *(const short8*)(Wthi + (c * 16 + m) * 128 + koff);
            short8 bl = *(const short8*)(Wtlo + (c * 16 + m) * 128 + koff);
            acc[0][c] = __builtin_amdgcn_mfma_f32_16x16x32_bf16(ah0, bh, acc[0][c], 0, 0, 0);
            acc[1][c] = __builtin_amdgcn_mfma_f32_16x16x32_bf16(ah1, bh, acc[1][c], 0, 0, 0);
            acc[0][c] = __builtin_amdgcn_mfma_f32_16x16x32_bf16(ah0, bl, acc[0][c], 0, 0, 0);
            acc[1][c] = __builtin_amdgcn_mfma_f32_16x16x32_bf16(ah1, bl, acc[1][c], 0, 0, 0);
        }
    }

    const int rb0 = r0 + q * 4;
    const int rb1 = r0 + 16 + q * 4;
    f32x4 dv0 = *(const f32x4*)(dinv + rb0);
    f32x4 dv1 = *(const f32x4*)(dinv + rb1);
#pragma unroll
    for (int c = 0; c < 8; ++c) {
        const int col = c * 16 + m;
#pragma unroll
        for (int r = 0; r < 4; ++r) {
            int row = rb0 + r;
            if (row < N_NODES) Yf[(size_t)row * 128 + col] = f2q(acc[0][c][r] * dv0[r]);
            row = rb1 + r;
            if (row < N_NODES) Yf[(size_t)row * 128 + col] = f2q(acc[1][c][r] * dv1[r]);
        }
    }
}

// ---------- layer-2 GEMM: Y2 = fp8((H @ W2) * dinv), H plain bf16 ----------
__global__ __launch_bounds__(256) void gemm2_mfma(const short* __restrict__ H,
                                                  const short* __restrict__ Wthi,
                                                  const short* __restrict__ Wtlo,
                                                  const float* __restrict__ dinv,
                                                  unsigned char* __restrict__ Yf) {
    const int t = threadIdx.x;
    const int w = t >> 6, lane = t & 63;
    const int m = lane & 15, q = lane >> 4;
    const int r0 = blockIdx.x * 128 + w * 32;

    f32x4 acc[2][4];
#pragma unroll
    for (int i = 0; i < 2; ++i)
#pragma unroll
        for (int c = 0; c < 4; ++c) acc[i][c] = (f32x4)(0.f);

#pragma unroll
    for (int kk = 0; kk < 4; ++kk) {
        const int koff = kk * 32 + q * 8;
        short8 ah0 = *(const short8*)(H + (size_t)(r0 + m) * 128 + koff);
        short8 ah1 = *(const short8*)(H + (size_t)(r0 + 16 + m) * 128 + koff);
#pragma unroll
        for (int c = 0; c < 4; ++c) {
            short8 bh = *(const short8*)(Wthi + (c * 16 + m) * 128 + koff);
            short8 bl = *(const short8*)(Wtlo + (c * 16 + m) * 128 + koff);
            acc[0][c] = __builtin_amdgcn_mfma_f32_16x16x32_bf16(ah0, bh, acc[0][c], 0, 0, 0);
            acc[1][c] = __builtin_amdgcn_mfma_f32_16x16x32_bf16(ah1, bh, acc[1][c], 0, 0, 0);
            acc[0][c] = __builtin_amdgcn_mfma_f32_16x16x32_bf16(ah0, bl, acc[0][c], 0, 0, 0);
            acc[1][c] = __builtin_amdgcn_mfma_f32_16x16x32_bf16(ah1, bl, acc[1][c], 0, 0, 0);
        }
    }

    const int rb0 = r0 + q * 4;
    const int rb1 = r0 + 16 + q * 4;
    f32x4 dv0 = *(const f32x4*)(dinv + rb0);
    f32x4 dv1 = *(const f32x4*)(dinv + rb1);
#pragma unroll
    for (int c = 0; c < 4; ++c) {
        const int col = c * 16 + m;
#pragma unroll
        for (int r = 0; r < 4; ++r) {
            int row = rb0 + r;
            if (row < N_NODES) Yf[(size_t)row * 64 + col] = f2q(acc[0][c][r] * dv0[r]);
            row = rb1 + r;
            if (row < N_NODES) Yf[(size_t)row * 64 + col] = f2q(acc[1][c][r] * dv1[r]);
        }
    }
}

// ---------- CSR aggregation, K=128 fp8: half-wave/edge, minimal epilogue ----------
__global__ __launch_bounds__(256) void agg_relu(const int* __restrict__ rowp,
                                                const int* __restrict__ srcs,
                                                const unsigned char* __restrict__ Yf,
                                                const float* __restrict__ dinv,
                                                const float* __restrict__ b,
                                                short* __restrict__ Hb) {
    int t = threadIdx.x;
    int lane = t & 63, w = t >> 6;
    int half = lane >> 5, li = lane & 31;     // 2 groups of 32 lanes
    int d = blockIdx.x * 4 + w;
    if (d >= N_NODES) return;
    const unsigned* Yu = (const unsigned*)Yf; // row = 32 uints (128 fp8)
    float a[4] = {0.f, 0.f, 0.f, 0.f};
    if (!half) acc4(a, Yu[(size_t)d * 32 + li]);  // self loop
    int e = rowp[d], end = rowp[d + 1];
    for (; e + 8 <= end; e += 8) {            // 8 edges: 4 loads in flight
        int s0 = srcs[e + half], s1 = srcs[e + 2 + half];
        int s2 = srcs[e + 4 + half], s3 = srcs[e + 6 + half];
        unsigned u0 = Yu[(size_t)s0 * 32 + li];
        unsigned u1 = Yu[(size_t)s1 * 32 + li];
        unsigned u2 = Yu[(size_t)s2 * 32 + li];
        unsigned u3 = Yu[(size_t)s3 * 32 + li];
        acc4(a, u0); acc4(a, u1); acc4(a, u2); acc4(a, u3);
    }
    for (; e < end; e += 2) {                 // masked remainder
        int idx = e + half;
        int s = srcs[(idx < end) ? idx : e];
        unsigned u = Yu[(size_t)s * 32 + li];
        if (idx < end) acc4(a, u);
    }
    // single merge level
#pragma unroll
    for (int i = 0; i < 4; ++i) a[i] += __shfl_xor(a[i], 32);
    if (!half) {                              // feats 4*li .. 4*li+3
        float sc = dinv[d];
        float4 bb = ((const float4*)b)[li];
        float v0 = fmaxf(sc * a[0] + bb.x, 0.f);
        float v1 = fmaxf(sc * a[1] + bb.y, 0.f);
        float v2 = fmaxf(sc * a[2] + bb.z, 0.f);
        float v3 = fmaxf(sc * a[3] + bb.w, 0.f);
        ((uint2*)Hb)[(size_t)d * 32 + li] = make_uint2(pk2(v0, v1), pk2(v2, v3));
    }
}

// ---------- CSR aggregation, K=64 fp8: quarter-wave/edge + slim log_softmax ----------
__global__ __launch_bounds__(256) void agg_lsm(const int* __restrict__ rowp,
                                               const int* __restrict__ srcs,
                                               const unsigned char* __restrict__ Yf,
                                               const float* __restrict__ dinv,
                                               const float* __restrict__ b,
                                               float* __restrict__ out) {
    int t = threadIdx.x;
    int lane = t & 63, w = t >> 6;
    int gi = lane >> 4, li = lane & 15;       // 4 groups of 16 lanes
    int d = blockIdx.x * 4 + w;
    if (d >= N_NODES) return;
    const unsigned* Yu = (const unsigned*)Yf; // row = 16 uints (64 fp8)
    float a[4] = {0.f, 0.f, 0.f, 0.f};
    if (gi == 0) acc4(a, Yu[(size_t)d * 16 + li]);  // self loop
    int e = rowp[d], end = rowp[d + 1];
    for (; e + 8 <= end; e += 8) {            // 8 edges: 2 loads in flight
        int s0 = srcs[e + gi], s1 = srcs[e + 4 + gi];
        unsigned u0 = Yu[(size_t)s0 * 16 + li];
        unsigned u1 = Yu[(size_t)s1 * 16 + li];
        acc4(a, u0); acc4(a, u1);
    }
    for (; e < end; e += 4) {                 // masked remainder
        int idx = e + gi;
        int s = srcs[(idx < end) ? idx : e];
        unsigned u = Yu[(size_t)s * 16 + li];
        if (idx < end) acc4(a, u);
    }
    // two merge levels -> all lanes hold totals for feats 4*li..4*li+3
#pragma unroll
    for (int i = 0; i < 4; ++i) {
        a[i] += __shfl_xor(a[i], 16);
        a[i] += __shfl_xor(a[i], 32);
    }
    float sc = dinv[d];
    float4 bb = ((const float4*)b)[li];
    float v0 = sc * a[0] + bb.x;
    float v1 = sc * a[1] + bb.y;
    float v2 = sc * a[2] + bb.z;
    float v3 = sc * a[3] + bb.w;
    float m = fmaxf(fmaxf(v0, v1), fmaxf(v2, v3));
#pragma unroll
    for (int o = 1; o <= 8; o <<= 1) m = fmaxf(m, __shfl_xor(m, o));
    float su = __expf(v0 - m) + __expf(v1 - m) + __expf(v2 - m) + __expf(v3 - m);
#pragma unroll
    for (int o = 1; o <= 8; o <<= 1) su += __shfl_xor(su, o);
    float ls = m + logf(su);
    if (gi == 0)
        ((float4*)out)[(size_t)d * 16 + li] =
            make_float4(v0 - ls, v1 - ls, v2 - ls, v3 - ls);
}

extern "C" void kernel_launch(void* const* d_in, const int* in_sizes, int n_in,
                              void* d_out, int out_size, void* d_ws, size_t ws_size,
                              hipStream_t stream) {
    const float* x  = (const float*)d_in[0];
    const float* W1 = (const float*)d_in[1];
    const float* b1 = (const float*)d_in[2];
    const float* W2 = (const float*)d_in[3];
    const float* b2 = (const float*)d_in[4];
    const int* edge = (const int*)d_in[5];
    const int* src = edge;
    const int* dst = edge + N_EDGES;
    float* out = (float*)d_out;

    char* ws = (char*)d_ws;
    int*           bcnt  = (int*)(ws + 0);            //     1,564
    int*           boffs = (int*)(ws + 2048);         //     1,568
    int*           bcur  = (int*)(ws + 4096);         //     1,564
    float*         dinv  = (float*)(ws + 6144);       //   400,384 (MROWS)
    int*           rowp  = (int*)(ws + 406528);       //   400,008
    int*           srcs  = (int*)(ws + 806912);       // 6,400,000
    unsigned*      pairs = (unsigned*)(ws + 7206912); // 6,400,000
    short*         w1hi  = (short*)(ws + 13606912);   //    32,768
    short*         w1lo  = (short*)(ws + 13639680);   //    32,768
    short*         w2hi  = (short*)(ws + 13672448);   //    16,384
    short*         w2lo  = (short*)(ws + 13688832);   //    16,384
    unsigned char* y1f   = (unsigned char*)(ws + 13705216); // 12,812,288 (MROWS*128 fp8)
    short*         h1b   = (short*)(ws + 26517504);   // 25,624,576 (MROWS*128 bf16)
    unsigned char* y2f   = (unsigned char*)(ws + 52142080); //  6,406,144 (MROWS*64 fp8)

    // ---- CSR build: bucket histogram -> scan -> scatter -> bucket-local fill ----
    hipMemsetAsync(bcnt, 0, NB * sizeof(int), stream);
    bucket_count<<<512, 256, 0, stream>>>(dst, bcnt);
    bucket_scan<<<1, 512, 0, stream>>>(bcnt, boffs, bcur);
    bucket_scatter<<<(N_EDGES + CH - 1) / CH, 256, 0, stream>>>(src, dst, bcur, pairs);
    csr_fill_bucket<<<NB, 256, 0, stream>>>(pairs, boffs, rowp, dinv, srcs);

    // ---- weight conversion ----
    convert_w<<<(128 * 128 + 64 * 128 + 255) / 256, 256, 0, stream>>>(W1, W2, w1hi, w1lo,
                                                                      w2hi, w2lo);

    // ---- layer 1 ----
    gemm1_mfma<<<MROWS / 128, 256, 0, stream>>>(x, w1hi, w1lo, dinv, y1f);
    agg_relu<<<(N_NODES + 3) / 4, 256, 0, stream>>>(rowp, srcs, y1f, dinv, b1, h1b);

    // ---- layer 2 ----
    gemm2_mfma<<<MROWS / 128, 256, 0, stream>>>(h1b, w2hi, w2lo, dinv, y2f);
    agg_lsm<<<(N_NODES + 3) / 4, 256, 0, stream>>>(rowp, srcs, y2f, dinv, b2, out);
}

// Round 11
// 328.270 us; speedup vs baseline: 1.0818x; 1.0169x over previous
//
#include <hip/hip_runtime.h>
#include <math.h>

#define N_NODES 100000
#define N_EDGES 1600000
#define NB 391              // dst buckets (d>>8), 256 nodes each
#define MROWS 100096        // 782*128, padded row count for guard-free tiles
#define CH 3200             // edges per bucket_scatter block -> 500 blocks
#define ZROW N_NODES        // sentinel zero row for edge-list padding

typedef __attribute__((ext_vector_type(8))) short short8;  // 8 bf16 = 4 VGPRs
typedef __attribute__((ext_vector_type(4))) float f32x4;
typedef __attribute__((ext_vector_type(2))) float f32x2;

__device__ __forceinline__ short f2b(float f) {            // fp32 -> bf16 RNE
    unsigned u = __float_as_uint(f);
    unsigned r = (u + 0x7FFFu + ((u >> 16) & 1u)) >> 16;
    return (short)r;
}
__device__ __forceinline__ float b2f(short s) {
    return __uint_as_float(((unsigned)(unsigned short)s) << 16);
}
__device__ __forceinline__ unsigned pk2(float a, float b) {
    return (unsigned)(unsigned short)f2b(a) | ((unsigned)(unsigned short)f2b(b) << 16);
}
// f32 -> fp8 e4m3 (OCP), single byte
__device__ __forceinline__ unsigned char f2q(float v) {
    return (unsigned char)(__builtin_amdgcn_cvt_pk_fp8_f32(v, 0.f, 0, false) & 0xFF);
}
// accumulate 4 fp8 (one uint) into a[0..3]
__device__ __forceinline__ void acc4(float* a, unsigned u) {
    f32x2 lo = __builtin_amdgcn_cvt_pk_f32_fp8((int)u, false);
    f32x2 hi = __builtin_amdgcn_cvt_pk_f32_fp8((int)u, true);
    a[0] += lo[0]; a[1] += lo[1]; a[2] += hi[0]; a[3] += hi[1];
}

// pack 8 fp32 -> 8 bf16 (RNE)
__device__ __forceinline__ short8 pack8(const float* __restrict__ p) {
    float4 v0 = ((const float4*)p)[0];
    float4 v1 = ((const float4*)p)[1];
    short8 h;
    h[0] = f2b(v0.x); h[1] = f2b(v0.y); h[2] = f2b(v0.z); h[3] = f2b(v0.w);
    h[4] = f2b(v1.x); h[5] = f2b(v1.y); h[6] = f2b(v1.z); h[7] = f2b(v1.w);
    return h;
}

// ---------- bucket histogram (LDS-staged) ----------
__global__ __launch_bounds__(256) void bucket_count(const int* __restrict__ dst,
                                                    int* __restrict__ bcnt) {
    __shared__ int h[NB];
    int t = threadIdx.x;
    for (int i = t; i < NB; i += 256) h[i] = 0;
    __syncthreads();
    for (int e = blockIdx.x * 256 + t; e < N_EDGES; e += gridDim.x * 256)
        atomicAdd(&h[dst[e] >> 8], 1);
    __syncthreads();
    for (int i = t; i < NB; i += 256)
        if (h[i]) atomicAdd(&bcnt[i], h[i]);
}

// ---------- bucket-level exclusive scan (one block) ----------
__global__ __launch_bounds__(512) void bucket_scan(const int* __restrict__ bcnt,
                                                   int* __restrict__ boffs,
                                                   int* __restrict__ bcur) {
    __shared__ int s[512];
    int t = threadIdx.x;
    int v = (t < NB) ? bcnt[t] : 0;
    s[t] = v;
    __syncthreads();
    for (int off = 1; off < 512; off <<= 1) {
        int u = (t >= off) ? s[t - off] : 0;
        __syncthreads();
        s[t] += u;
        __syncthreads();
    }
    if (t < NB) {
        int ex = s[t] - v;
        boffs[t] = ex;
        bcur[t] = ex;
    }
    if (t == 0) boffs[NB] = N_EDGES;
}

// ---------- scatter edges into bucket-grouped packed list ----------
// packed word: (d&255)<<24 | src   (src < 2^24)
__global__ __launch_bounds__(256) void bucket_scatter(const int* __restrict__ src,
                                                      const int* __restrict__ dst,
                                                      int* __restrict__ bcur,
                                                      unsigned* __restrict__ pairs) {
    __shared__ unsigned lw[CH];
    __shared__ short lb[CH];
    __shared__ int cnt[NB];
    __shared__ int lstart[NB];
    int t = threadIdx.x;
    int e0 = blockIdx.x * CH;
    int n = min(CH, N_EDGES - e0);
    for (int i = t; i < NB; i += 256) cnt[i] = 0;
    __syncthreads();
    for (int i = t; i < n; i += 256) {
        int s = src[e0 + i], d = dst[e0 + i];
        lw[i] = ((unsigned)(d & 255) << 24) | (unsigned)s;
        int b = d >> 8;
        lb[i] = (short)b;
        atomicAdd(&cnt[b], 1);
    }
    __syncthreads();
    for (int b = t; b < NB; b += 256) {
        int c = cnt[b];
        lstart[b] = c ? atomicAdd(&bcur[b], c) : 0;
        cnt[b] = 0;  // reuse as local cursor
    }
    __syncthreads();
    for (int i = t; i < n; i += 256) {
        int b = lb[i];
        int lo = atomicAdd(&cnt[b], 1);
        pairs[lstart[b] + lo] = lw[i];
    }
}

// ---------- bucket-local CSR fill with 8-padding; derives rowp/rend/dinv ----------
__global__ __launch_bounds__(256) void csr_fill_bucket(const unsigned* __restrict__ pairs,
                                                       const int* __restrict__ boffs,
                                                       int* __restrict__ rowp,
                                                       int* __restrict__ rend,
                                                       float* __restrict__ dinv,
                                                       int* __restrict__ srcs) {
    __shared__ int lcnt[256];
    __shared__ int ls[256];
    int t = threadIdx.x, b = blockIdx.x, base = b << 8;
    lcnt[t] = 0;
    __syncthreads();
    int lo_e = boffs[b], hi_e = boffs[b + 1];
    for (int i = lo_e + t; i < hi_e; i += 256)
        atomicAdd(&lcnt[pairs[i] >> 24], 1);
    __syncthreads();
    int c = lcnt[t];
    int cpad = (c + 7) & ~7;          // pad each node's list to multiple of 8
    ls[t] = cpad;
    __syncthreads();
    for (int off = 1; off < 256; off <<= 1) {
        int u = (t >= off) ? ls[t - off] : 0;
        __syncthreads();
        ls[t] += u;
        __syncthreads();
    }
    int pbase = ((lo_e + 7) & ~7) + b * 2048;   // 8-aligned padded bucket base
    int rp = pbase + ls[t] - cpad;
    int node = base + t;
    if (node < N_NODES) {
        rowp[node] = rp;
        rend[node] = rp + cpad;
        dinv[node] = rsqrtf((float)(c + 1));
    }
    __syncthreads();
    lcnt[t] = rp;                      // reuse as global cursor
    __syncthreads();
    for (int i = lo_e + t; i < hi_e; i += 256) {
        unsigned p = pairs[i];
        int li = p >> 24;
        int pos = atomicAdd(&lcnt[li], 1);
        srcs[pos] = (int)(p & 0xFFFFFFu);
    }
    __syncthreads();
    // pad fill: thread t pads its own node with the zero-row sentinel
    for (int i = lcnt[t], stop = rp + cpad; i < stop; ++i) srcs[i] = ZROW;
}

// ---------- W1 [128][128] + W2 [128][64] fp32 -> Wt [N][128] split bf16 ----------
__global__ __launch_bounds__(256) void convert_w(const float* __restrict__ W1,
                                                 const float* __restrict__ W2,
                                                 short* __restrict__ w1hi,
                                                 short* __restrict__ w1lo,
                                                 short* __restrict__ w2hi,
                                                 short* __restrict__ w2lo) {
    int id = blockIdx.x * 256 + threadIdx.x;
    if (id < 128 * 128) {
        int n = id >> 7, k = id & 127;
        float v = W1[k * 128 + n];
        short h = f2b(v);
        w1hi[id] = h;
        w1lo[id] = f2b(v - b2f(h));
    } else if (id < 128 * 128 + 64 * 128) {
        int j = id - 128 * 128;
        int n = j >> 7, k = j & 127;
        float v = W2[k * 64 + n];
        short h = f2b(v);
        w2hi[j] = h;
        w2lo[j] = f2b(v - b2f(h));
    }
}

// ---------- layer-1 GEMM: Y1 = fp8((X @ W1) * dinv); A=bf16(X), B split ----------
__global__ __launch_bounds__(256) void gemm1_mfma(const float* __restrict__ X,
                                                  const short* __restrict__ Wthi,
                                                  const short* __restrict__ Wtlo,
                                                  const float* __restrict__ dinv,
                                                  unsigned char* __restrict__ Yf) {
    const int t = threadIdx.x;
    const int w = t >> 6, lane = t & 63;
    const int m = lane & 15, q = lane >> 4;
    const int r0 = blockIdx.x * 128 + w * 32;
    const int ra = min(r0 + m, N_NODES - 1);
    const int rb = min(r0 + 16 + m, N_NODES - 1);

    f32x4 acc[2][8];
#pragma unroll
    for (int i = 0; i < 2; ++i)
#pragma unroll
        for (int c = 0; c < 8; ++c) acc[i][c] = (f32x4)(0.f);

#pragma unroll
    for (int kk = 0; kk < 4; ++kk) {
        const int koff = kk * 32 + q * 8;
        short8 ah0 = pack8(X + (size_t)ra * 128 + koff);
        short8 ah1 = pack8(X + (size_t)rb * 128 + koff);
#pragma unroll
        for (int c = 0; c < 8; ++c) {
            short8 bh = *(const short8*)(Wthi + (c * 16 + m) * 128 + koff);
            short8 bl = *(const short8*)(Wtlo + (c * 16 + m) * 128 + koff);
            acc[0][c] = __builtin_amdgcn_mfma_f32_16x16x32_bf16(ah0, bh, acc[0][c], 0, 0, 0);
            acc[1][c] = __builtin_amdgcn_mfma_f32_16x16x32_bf16(ah1, bh, acc[1][c], 0, 0, 0);
            acc[0][c] = __builtin_amdgcn_mfma_f32_16x16x32_bf16(ah0, bl, acc[0][c], 0, 0, 0);
            acc[1][c] = __builtin_amdgcn_mfma_f32_16x16x32_bf16(ah1, bl, acc[1][c], 0, 0, 0);
        }
    }

    const int rb0 = r0 + q * 4;
    const int rb1 = r0 + 16 + q * 4;
    f32x4 dv0 = *(const f32x4*)(dinv + rb0);
    f32x4 dv1 = *(const f32x4*)(dinv + rb1);
#pragma unroll
    for (int c = 0; c < 8; ++c) {
        const int col = c * 16 + m;
#pragma unroll
        for (int r = 0; r < 4; ++r) {
            int row = rb0 + r;
            if (row < N_NODES) Yf[(size_t)row * 128 + col] = f2q(acc[0][c][r] * dv0[r]);
            row = rb1 + r;
            if (row < N_NODES) Yf[(size_t)row * 128 + col] = f2q(acc[1][c][r] * dv1[r]);
        }
    }
}

// ---------- layer-2 GEMM: Y2 = fp8((H @ W2) * dinv), H plain bf16 ----------
__global__ __launch_bounds__(256) void gemm2_mfma(const short* __restrict__ H,
                                                  const short* __restrict__ Wthi,
                                                  const short* __restrict__ Wtlo,
                                                  const float* __restrict__ dinv,
                                                  unsigned char* __restrict__ Yf) {
    const int t = threadIdx.x;
    const int w = t >> 6, lane = t & 63;
    const int m = lane & 15, q = lane >> 4;
    const int r0 = blockIdx.x * 128 + w * 32;

    f32x4 acc[2][4];
#pragma unroll
    for (int i = 0; i < 2; ++i)
#pragma unroll
        for (int c = 0; c < 4; ++c) acc[i][c] = (f32x4)(0.f);

#pragma unroll
    for (int kk = 0; kk < 4; ++kk) {
        const int koff = kk * 32 + q * 8;
        short8 ah0 = *(const short8*)(H + (size_t)(r0 + m) * 128 + koff);
        short8 ah1 = *(const short8*)(H + (size_t)(r0 + 16 + m) * 128 + koff);
#pragma unroll
        for (int c = 0; c < 4; ++c) {
            short8 bh = *(const short8*)(Wthi + (c * 16 + m) * 128 + koff);
            short8 bl = *(const short8*)(Wtlo + (c * 16 + m) * 128 + koff);
            acc[0][c] = __builtin_amdgcn_mfma_f32_16x16x32_bf16(ah0, bh, acc[0][c], 0, 0, 0);
            acc[1][c] = __builtin_amdgcn_mfma_f32_16x16x32_bf16(ah1, bh, acc[1][c], 0, 0, 0);
            acc[0][c] = __builtin_amdgcn_mfma_f32_16x16x32_bf16(ah0, bl, acc[0][c], 0, 0, 0);
            acc[1][c] = __builtin_amdgcn_mfma_f32_16x16x32_bf16(ah1, bl, acc[1][c], 0, 0, 0);
        }
    }

    const int rb0 = r0 + q * 4;
    const int rb1 = r0 + 16 + q * 4;
    f32x4 dv0 = *(const f32x4*)(dinv + rb0);
    f32x4 dv1 = *(const f32x4*)(dinv + rb1);
#pragma unroll
    for (int c = 0; c < 4; ++c) {
        const int col = c * 16 + m;
#pragma unroll
        for (int r = 0; r < 4; ++r) {
            int row = rb0 + r;
            if (row < N_NODES) Yf[(size_t)row * 64 + col] = f2q(acc[0][c][r] * dv0[r]);
            row = rb1 + r;
            if (row < N_NODES) Yf[(size_t)row * 64 + col] = f2q(acc[1][c][r] * dv1[r]);
        }
    }
}

// ---------- CSR aggregation, K=128 fp8: half-wave/edge, padded (no remainder) ----------
__global__ __launch_bounds__(256) void agg_relu(const int* __restrict__ rowp,
                                                const int* __restrict__ rend,
                                                const int* __restrict__ srcs,
                                                const unsigned char* __restrict__ Yf,
                                                const float* __restrict__ dinv,
                                                const float* __restrict__ b,
                                                short* __restrict__ Hb) {
    int t = threadIdx.x;
    int lane = t & 63, w = t >> 6;
    int half = lane >> 5, li = lane & 31;     // 2 groups of 32 lanes
    int d = blockIdx.x * 4 + w;
    if (d >= N_NODES) return;
    const unsigned fo = (unsigned)(li << 2);
    float a[4] = {0.f, 0.f, 0.f, 0.f};
    if (!half) acc4(a, *(const unsigned*)(Yf + (((unsigned)d << 7) + fo)));  // self loop
    int e = rowp[d], end = rend[d];
    for (; e < end; e += 8) {                 // uniform: list padded to x8
        uint4 sv = *(const uint4*)(srcs + e + 4 * half);
        unsigned u0 = *(const unsigned*)(Yf + (((unsigned)sv.x << 7) + fo));
        unsigned u1 = *(const unsigned*)(Yf + (((unsigned)sv.y << 7) + fo));
        unsigned u2 = *(const unsigned*)(Yf + (((unsigned)sv.z << 7) + fo));
        unsigned u3 = *(const unsigned*)(Yf + (((unsigned)sv.w << 7) + fo));
        acc4(a, u0); acc4(a, u1); acc4(a, u2); acc4(a, u3);
    }
#pragma unroll
    for (int i = 0; i < 4; ++i) a[i] += __shfl_xor(a[i], 32);
    if (!half) {                              // feats 4*li .. 4*li+3
        float sc = dinv[d];
        float4 bb = ((const float4*)b)[li];
        float v0 = fmaxf(sc * a[0] + bb.x, 0.f);
        float v1 = fmaxf(sc * a[1] + bb.y, 0.f);
        float v2 = fmaxf(sc * a[2] + bb.z, 0.f);
        float v3 = fmaxf(sc * a[3] + bb.w, 0.f);
        ((uint2*)Hb)[(size_t)d * 32 + li] = make_uint2(pk2(v0, v1), pk2(v2, v3));
    }
}

// ---------- CSR aggregation, K=64 fp8: quarter-wave/edge, padded + log_softmax ----------
__global__ __launch_bounds__(256) void agg_lsm(const int* __restrict__ rowp,
                                               const int* __restrict__ rend,
                                               const int* __restrict__ srcs,
                                               const unsigned char* __restrict__ Yf,
                                               const float* __restrict__ dinv,
                                               const float* __restrict__ b,
                                               float* __restrict__ out) {
    int t = threadIdx.x;
    int lane = t & 63, w = t >> 6;
    int gi = lane >> 4, li = lane & 15;       // 4 groups of 16 lanes
    int d = blockIdx.x * 4 + w;
    if (d >= N_NODES) return;
    const unsigned fo = (unsigned)(li << 2);
    float a[4] = {0.f, 0.f, 0.f, 0.f};
    if (gi == 0) acc4(a, *(const unsigned*)(Yf + (((unsigned)d << 6) + fo)));  // self loop
    int e = rowp[d], end = rend[d];
    for (; e < end; e += 8) {                 // uniform: list padded to x8
        uint2 sv = *(const uint2*)(srcs + e + 2 * gi);
        unsigned u0 = *(const unsigned*)(Yf + (((unsigned)sv.x << 6) + fo));
        unsigned u1 = *(const unsigned*)(Yf + (((unsigned)sv.y << 6) + fo));
        acc4(a, u0); acc4(a, u1);
    }
#pragma unroll
    for (int i = 0; i < 4; ++i) {
        a[i] += __shfl_xor(a[i], 16);
        a[i] += __shfl_xor(a[i], 32);
    }
    float sc = dinv[d];
    float4 bb = ((const float4*)b)[li];
    float v0 = sc * a[0] + bb.x;
    float v1 = sc * a[1] + bb.y;
    float v2 = sc * a[2] + bb.z;
    float v3 = sc * a[3] + bb.w;
    float m = fmaxf(fmaxf(v0, v1), fmaxf(v2, v3));
#pragma unroll
    for (int o = 1; o <= 8; o <<= 1) m = fmaxf(m, __shfl_xor(m, o));
    float su = __expf(v0 - m) + __expf(v1 - m) + __expf(v2 - m) + __expf(v3 - m);
#pragma unroll
    for (int o = 1; o <= 8; o <<= 1) su += __shfl_xor(su, o);
    float ls = m + logf(su);
    if (gi == 0)
        ((float4*)out)[(size_t)d * 16 + li] =
            make_float4(v0 - ls, v1 - ls, v2 - ls, v3 - ls);
}

extern "C" void kernel_launch(void* const* d_in, const int* in_sizes, int n_in,
                              void* d_out, int out_size, void* d_ws, size_t ws_size,
                              hipStream_t stream) {
    const float* x  = (const float*)d_in[0];
    const float* W1 = (const float*)d_in[1];
    const float* b1 = (const float*)d_in[2];
    const float* W2 = (const float*)d_in[3];
    const float* b2 = (const float*)d_in[4];
    const int* edge = (const int*)d_in[5];
    const int* src = edge;
    const int* dst = edge + N_EDGES;
    float* out = (float*)d_out;

    char* ws = (char*)d_ws;
    int*           bcnt  = (int*)(ws + 0);             //     1,564
    int*           boffs = (int*)(ws + 2048);          //     1,568
    int*           bcur  = (int*)(ws + 4096);          //     1,564
    float*         dinv  = (float*)(ws + 6144);        //   400,384 (MROWS)
    int*           rowp  = (int*)(ws + 406528);        //   400,000
    int*           rend  = (int*)(ws + 806528);        //   400,000
    int*           srcs  = (int*)(ws + 1206528);       // 9,700,000 (padded CSR)
    unsigned*      pairs = (unsigned*)(ws + 10906624); // 6,400,000
    short*         w1hi  = (short*)(ws + 17306624);    //    32,768
    short*         w1lo  = (short*)(ws + 17339392);    //    32,768
    short*         w2hi  = (short*)(ws + 17372160);    //    16,384
    short*         w2lo  = (short*)(ws + 17388544);    //    16,384
    unsigned char* y1f   = (unsigned char*)(ws + 17404928); // 12,812,288 (MROWS*128 fp8)
    short*         h1b   = (short*)(ws + 30217216);    // 25,624,576 (MROWS*128 bf16)
    unsigned char* y2f   = (unsigned char*)(ws + 55841792); //  6,406,144 (MROWS*64 fp8)
    // ends ~62.2 MB

    // ---- zero the sentinel rows (ZROW = N_NODES) for padded gathers ----
    hipMemsetAsync(y1f + (size_t)N_NODES * 128, 0, 128, stream);
    hipMemsetAsync(y2f + (size_t)N_NODES * 64, 0, 64, stream);

    // ---- CSR build: bucket histogram -> scan -> scatter -> padded bucket fill ----
    hipMemsetAsync(bcnt, 0, NB * sizeof(int), stream);
    bucket_count<<<512, 256, 0, stream>>>(dst, bcnt);
    bucket_scan<<<1, 512, 0, stream>>>(bcnt, boffs, bcur);
    bucket_scatter<<<(N_EDGES + CH - 1) / CH, 256, 0, stream>>>(src, dst, bcur, pairs);
    csr_fill_bucket<<<NB, 256, 0, stream>>>(pairs, boffs, rowp, rend, dinv, srcs);

    // ---- weight conversion ----
    convert_w<<<(128 * 128 + 64 * 128 + 255) / 256, 256, 0, stream>>>(W1, W2, w1hi, w1lo,
                                                                      w2hi, w2lo);

    // ---- layer 1 ----
    gemm1_mfma<<<MROWS / 128, 256, 0, stream>>>(x, w1hi, w1lo, dinv, y1f);
    agg_relu<<<(N_NODES + 3) / 4, 256, 0, stream>>>(rowp, rend, srcs, y1f, dinv, b1, h1b);

    // ---- layer 2 ----
    gemm2_mfma<<<MROWS / 128, 256, 0, stream>>>(h1b, w2hi, w2lo, dinv, y2f);
    agg_lsm<<<(N_NODES + 3) / 4, 256, 0, stream>>>(rowp, rend, srcs, y2f, dinv, b2, out);
}

// Round 12
// 292.692 us; speedup vs baseline: 1.2133x; 1.1216x over previous
//
#include <hip/hip_runtime.h>
#include <math.h>

#define N_NODES 100000
#define N_EDGES 1600000
#define NB 391              // dst buckets (d>>8), 256 nodes each
#define MROWS 100096        // 782*128, padded row count for guard-free tiles
#define CH 3200             // edges per bucket_scatter block -> 500 blocks
#define ZROW N_NODES        // sentinel zero row for edge-list padding

typedef __attribute__((ext_vector_type(8))) short short8;  // 8 bf16 = 4 VGPRs
typedef __attribute__((ext_vector_type(4))) float f32x4;
typedef __attribute__((ext_vector_type(2))) float f32x2;

__device__ __forceinline__ short f2b(float f) {            // fp32 -> bf16 RNE
    unsigned u = __float_as_uint(f);
    unsigned r = (u + 0x7FFFu + ((u >> 16) & 1u)) >> 16;
    return (short)r;
}
__device__ __forceinline__ unsigned pk2(float a, float b) {
    return (unsigned)(unsigned short)f2b(a) | ((unsigned)(unsigned short)f2b(b) << 16);
}
// f32 -> fp8 e4m3 (OCP), single byte
__device__ __forceinline__ unsigned char f2q(float v) {
    return (unsigned char)(__builtin_amdgcn_cvt_pk_fp8_f32(v, 0.f, 0, false) & 0xFF);
}
// accumulate 4 fp8 (one uint) into a[0..3]
__device__ __forceinline__ void acc4(float* a, unsigned u) {
    f32x2 lo = __builtin_amdgcn_cvt_pk_f32_fp8((int)u, false);
    f32x2 hi = __builtin_amdgcn_cvt_pk_f32_fp8((int)u, true);
    a[0] += lo[0]; a[1] += lo[1]; a[2] += hi[0]; a[3] += hi[1];
}

// pack 8 fp32 -> 8 bf16 (truncate; 1 v_perm per 2 elems)
__device__ __forceinline__ short8 pack8t(const float* __restrict__ p) {
    float4 v0 = ((const float4*)p)[0];
    float4 v1 = ((const float4*)p)[1];
    union { unsigned u[4]; short8 s; } r;
    r.u[0] = __builtin_amdgcn_perm(__float_as_uint(v0.y), __float_as_uint(v0.x), 0x07060302u);
    r.u[1] = __builtin_amdgcn_perm(__float_as_uint(v0.w), __float_as_uint(v0.z), 0x07060302u);
    r.u[2] = __builtin_amdgcn_perm(__float_as_uint(v1.y), __float_as_uint(v1.x), 0x07060302u);
    r.u[3] = __builtin_amdgcn_perm(__float_as_uint(v1.w), __float_as_uint(v1.z), 0x07060302u);
    return r.s;
}

// ---------- bucket histogram (LDS-staged) ----------
__global__ __launch_bounds__(256) void bucket_count(const int* __restrict__ dst,
                                                    int* __restrict__ bcnt) {
    __shared__ int h[NB];
    int t = threadIdx.x;
    for (int i = t; i < NB; i += 256) h[i] = 0;
    __syncthreads();
    for (int e = blockIdx.x * 256 + t; e < N_EDGES; e += gridDim.x * 256)
        atomicAdd(&h[dst[e] >> 8], 1);
    __syncthreads();
    for (int i = t; i < NB; i += 256)
        if (h[i]) atomicAdd(&bcnt[i], h[i]);
}

// ---------- bucket-level exclusive scan (one block) ----------
__global__ __launch_bounds__(512) void bucket_scan(const int* __restrict__ bcnt,
                                                   int* __restrict__ boffs,
                                                   int* __restrict__ bcur) {
    __shared__ int s[512];
    int t = threadIdx.x;
    int v = (t < NB) ? bcnt[t] : 0;
    s[t] = v;
    __syncthreads();
    for (int off = 1; off < 512; off <<= 1) {
        int u = (t >= off) ? s[t - off] : 0;
        __syncthreads();
        s[t] += u;
        __syncthreads();
    }
    if (t < NB) {
        int ex = s[t] - v;
        boffs[t] = ex;
        bcur[t] = ex;
    }
    if (t == 0) boffs[NB] = N_EDGES;
}

// ---------- scatter edges into bucket-grouped packed list ----------
// packed word: (d&255)<<24 | src   (src < 2^24)
__global__ __launch_bounds__(256) void bucket_scatter(const int* __restrict__ src,
                                                      const int* __restrict__ dst,
                                                      int* __restrict__ bcur,
                                                      unsigned* __restrict__ pairs) {
    __shared__ unsigned lw[CH];
    __shared__ short lb[CH];
    __shared__ int cnt[NB];
    __shared__ int lstart[NB];
    int t = threadIdx.x;
    int e0 = blockIdx.x * CH;
    int n = min(CH, N_EDGES - e0);
    for (int i = t; i < NB; i += 256) cnt[i] = 0;
    __syncthreads();
    for (int i = t; i < n; i += 256) {
        int s = src[e0 + i], d = dst[e0 + i];
        lw[i] = ((unsigned)(d & 255) << 24) | (unsigned)s;
        int b = d >> 8;
        lb[i] = (short)b;
        atomicAdd(&cnt[b], 1);
    }
    __syncthreads();
    for (int b = t; b < NB; b += 256) {
        int c = cnt[b];
        lstart[b] = c ? atomicAdd(&bcur[b], c) : 0;
        cnt[b] = 0;  // reuse as local cursor
    }
    __syncthreads();
    for (int i = t; i < n; i += 256) {
        int b = lb[i];
        int lo = atomicAdd(&cnt[b], 1);
        pairs[lstart[b] + lo] = lw[i];
    }
}

// ---------- bucket-local CSR fill with 8-padding; derives rowp/rend/dinv ----------
__global__ __launch_bounds__(256) void csr_fill_bucket(const unsigned* __restrict__ pairs,
                                                       const int* __restrict__ boffs,
                                                       int* __restrict__ rowp,
                                                       int* __restrict__ rend,
                                                       float* __restrict__ dinv,
                                                       int* __restrict__ srcs) {
    __shared__ int lcnt[256];
    __shared__ int ls[256];
    int t = threadIdx.x, b = blockIdx.x, base = b << 8;
    lcnt[t] = 0;
    __syncthreads();
    int lo_e = boffs[b], hi_e = boffs[b + 1];
    for (int i = lo_e + t; i < hi_e; i += 256)
        atomicAdd(&lcnt[pairs[i] >> 24], 1);
    __syncthreads();
    int c = lcnt[t];
    int cpad = (c + 7) & ~7;          // pad each node's list to multiple of 8
    ls[t] = cpad;
    __syncthreads();
    for (int off = 1; off < 256; off <<= 1) {
        int u = (t >= off) ? ls[t - off] : 0;
        __syncthreads();
        ls[t] += u;
        __syncthreads();
    }
    int pbase = ((lo_e + 7) & ~7) + b * 2048;   // 8-aligned padded bucket base
    int rp = pbase + ls[t] - cpad;
    int node = base + t;
    if (node < N_NODES) {
        rowp[node] = rp;
        rend[node] = rp + cpad;
        dinv[node] = rsqrtf((float)(c + 1));
    }
    __syncthreads();
    lcnt[t] = rp;                      // reuse as global cursor
    __syncthreads();
    for (int i = lo_e + t; i < hi_e; i += 256) {
        unsigned p = pairs[i];
        int li = p >> 24;
        int pos = atomicAdd(&lcnt[li], 1);
        srcs[pos] = (int)(p & 0xFFFFFFu);
    }
    __syncthreads();
    // pad fill: thread t pads its own node with the zero-row sentinel
    for (int i = lcnt[t], stop = rp + cpad; i < stop; ++i) srcs[i] = ZROW;
}

// ---------- W1 [128][128] + W2 [128][64] fp32 -> Wt [N][128] bf16 ----------
__global__ __launch_bounds__(256) void convert_w(const float* __restrict__ W1,
                                                 const float* __restrict__ W2,
                                                 short* __restrict__ w1h,
                                                 short* __restrict__ w2h) {
    int id = blockIdx.x * 256 + threadIdx.x;
    if (id < 128 * 128) {
        int n = id >> 7, k = id & 127;
        w1h[id] = f2b(W1[k * 128 + n]);
    } else if (id < 128 * 128 + 64 * 128) {
        int j = id - 128 * 128;
        int n = j >> 7, k = j & 127;
        w2h[j] = f2b(W2[k * 64 + n]);
    }
}

// ---------- layer-1 GEMM: Y1 = fp8((X @ W1) * dinv); W in LDS, 16 rows/wave ----------
__global__ __launch_bounds__(512) void gemm1_mfma(const float* __restrict__ X,
                                                  const short* __restrict__ Wt,
                                                  const float* __restrict__ dinv,
                                                  unsigned char* __restrict__ Yf) {
    __shared__ short Ws[128 * 128];   // 32 KB
    const int t = threadIdx.x;
    for (int i = t * 8; i < 128 * 128; i += 512 * 8)
        *(short8*)(Ws + i) = *(const short8*)(Wt + i);
    __syncthreads();

    const int w = t >> 6, lane = t & 63;
    const int m = lane & 15, q = lane >> 4;
    const int r0 = blockIdx.x * 128 + w * 16;
    const int ra = min(r0 + m, N_NODES - 1);

    f32x4 acc[8];
#pragma unroll
    for (int c = 0; c < 8; ++c) acc[c] = (f32x4)(0.f);

#pragma unroll
    for (int kk = 0; kk < 4; ++kk) {
        const int koff = kk * 32 + q * 8;
        short8 a = pack8t(X + (size_t)ra * 128 + koff);
#pragma unroll
        for (int c = 0; c < 8; ++c) {
            short8 bh = *(const short8*)(Ws + (c * 16 + m) * 128 + koff);
            acc[c] = __builtin_amdgcn_mfma_f32_16x16x32_bf16(a, bh, acc[c], 0, 0, 0);
        }
    }

    // C/D layout: col=lane&15, row=q*4+reg  [verified m89/m91]
    const int rb0 = r0 + q * 4;
    f32x4 dv = *(const f32x4*)(dinv + rb0);
#pragma unroll
    for (int c = 0; c < 8; ++c) {
        const int col = c * 16 + m;
#pragma unroll
        for (int r = 0; r < 4; ++r) {
            int row = rb0 + r;
            if (row < N_NODES) Yf[(size_t)row * 128 + col] = f2q(acc[c][r] * dv[r]);
        }
    }
}

// ---------- layer-2 GEMM: Y2 = fp8((H @ W2) * dinv); W in LDS, 16 rows/wave ----------
__global__ __launch_bounds__(512) void gemm2_mfma(const short* __restrict__ H,
                                                  const short* __restrict__ Wt,
                                                  const float* __restrict__ dinv,
                                                  unsigned char* __restrict__ Yf) {
    __shared__ short Ws[64 * 128];    // 16 KB
    const int t = threadIdx.x;
    for (int i = t * 8; i < 64 * 128; i += 512 * 8)
        *(short8*)(Ws + i) = *(const short8*)(Wt + i);
    __syncthreads();

    const int w = t >> 6, lane = t & 63;
    const int m = lane & 15, q = lane >> 4;
    const int r0 = blockIdx.x * 128 + w * 16;

    f32x4 acc[4];
#pragma unroll
    for (int c = 0; c < 4; ++c) acc[c] = (f32x4)(0.f);

#pragma unroll
    for (int kk = 0; kk < 4; ++kk) {
        const int koff = kk * 32 + q * 8;
        short8 a = *(const short8*)(H + (size_t)(r0 + m) * 128 + koff);
#pragma unroll
        for (int c = 0; c < 4; ++c) {
            short8 bh = *(const short8*)(Ws + (c * 16 + m) * 128 + koff);
            acc[c] = __builtin_amdgcn_mfma_f32_16x16x32_bf16(a, bh, acc[c], 0, 0, 0);
        }
    }

    const int rb0 = r0 + q * 4;
    f32x4 dv = *(const f32x4*)(dinv + rb0);
#pragma unroll
    for (int c = 0; c < 4; ++c) {
        const int col = c * 16 + m;
#pragma unroll
        for (int r = 0; r < 4; ++r) {
            int row = rb0 + r;
            if (row < N_NODES) Yf[(size_t)row * 64 + col] = f2q(acc[c][r] * dv[r]);
        }
    }
}

// ---------- CSR aggregation, K=128 fp8: half-wave/edge, padded (no remainder) ----------
__global__ __launch_bounds__(256) void agg_relu(const int* __restrict__ rowp,
                                                const int* __restrict__ rend,
                                                const int* __restrict__ srcs,
                                                const unsigned char* __restrict__ Yf,
                                                const float* __restrict__ dinv,
                                                const float* __restrict__ b,
                                                short* __restrict__ Hb) {
    int t = threadIdx.x;
    int lane = t & 63, w = t >> 6;
    int half = lane >> 5, li = lane & 31;     // 2 groups of 32 lanes
    int d = blockIdx.x * 4 + w;
    if (d >= N_NODES) return;
    const unsigned fo = (unsigned)(li << 2);
    float a[4] = {0.f, 0.f, 0.f, 0.f};
    if (!half) acc4(a, *(const unsigned*)(Yf + (((unsigned)d << 7) + fo)));  // self loop
    int e = rowp[d], end = rend[d];
    for (; e < end; e += 8) {                 // uniform: list padded to x8
        uint4 sv = *(const uint4*)(srcs + e + 4 * half);
        unsigned u0 = *(const unsigned*)(Yf + (((unsigned)sv.x << 7) + fo));
        unsigned u1 = *(const unsigned*)(Yf + (((unsigned)sv.y << 7) + fo));
        unsigned u2 = *(const unsigned*)(Yf + (((unsigned)sv.z << 7) + fo));
        unsigned u3 = *(const unsigned*)(Yf + (((unsigned)sv.w << 7) + fo));
        acc4(a, u0); acc4(a, u1); acc4(a, u2); acc4(a, u3);
    }
#pragma unroll
    for (int i = 0; i < 4; ++i) a[i] += __shfl_xor(a[i], 32);
    if (!half) {                              // feats 4*li .. 4*li+3
        float sc = dinv[d];
        float4 bb = ((const float4*)b)[li];
        float v0 = fmaxf(sc * a[0] + bb.x, 0.f);
        float v1 = fmaxf(sc * a[1] + bb.y, 0.f);
        float v2 = fmaxf(sc * a[2] + bb.z, 0.f);
        float v3 = fmaxf(sc * a[3] + bb.w, 0.f);
        ((uint2*)Hb)[(size_t)d * 32 + li] = make_uint2(pk2(v0, v1), pk2(v2, v3));
    }
}

// ---------- CSR aggregation, K=64 fp8: quarter-wave/edge, padded + log_softmax ----------
__global__ __launch_bounds__(256) void agg_lsm(const int* __restrict__ rowp,
                                               const int* __restrict__ rend,
                                               const int* __restrict__ srcs,
                                               const unsigned char* __restrict__ Yf,
                                               const float* __restrict__ dinv,
                                               const float* __restrict__ b,
                                               float* __restrict__ out) {
    int t = threadIdx.x;
    int lane = t & 63, w = t >> 6;
    int gi = lane >> 4, li = lane & 15;       // 4 groups of 16 lanes
    int d = blockIdx.x * 4 + w;
    if (d >= N_NODES) return;
    const unsigned fo = (unsigned)(li << 2);
    float a[4] = {0.f, 0.f, 0.f, 0.f};
    if (gi == 0) acc4(a, *(const unsigned*)(Yf + (((unsigned)d << 6) + fo)));  // self loop
    int e = rowp[d], end = rend[d];
    for (; e < end; e += 8) {                 // uniform: list padded to x8
        uint2 sv = *(const uint2*)(srcs + e + 2 * gi);
        unsigned u0 = *(const unsigned*)(Yf + (((unsigned)sv.x << 6) + fo));
        unsigned u1 = *(const unsigned*)(Yf + (((unsigned)sv.y << 6) + fo));
        acc4(a, u0); acc4(a, u1);
    }
#pragma unroll
    for (int i = 0; i < 4; ++i) {
        a[i] += __shfl_xor(a[i], 16);
        a[i] += __shfl_xor(a[i], 32);
    }
    float sc = dinv[d];
    float4 bb = ((const float4*)b)[li];
    float v0 = sc * a[0] + bb.x;
    float v1 = sc * a[1] + bb.y;
    float v2 = sc * a[2] + bb.z;
    float v3 = sc * a[3] + bb.w;
    float m = fmaxf(fmaxf(v0, v1), fmaxf(v2, v3));
#pragma unroll
    for (int o = 1; o <= 8; o <<= 1) m = fmaxf(m, __shfl_xor(m, o));
    float su = __expf(v0 - m) + __expf(v1 - m) + __expf(v2 - m) + __expf(v3 - m);
#pragma unroll
    for (int o = 1; o <= 8; o <<= 1) su += __shfl_xor(su, o);
    float ls = m + logf(su);
    if (gi == 0)
        ((float4*)out)[(size_t)d * 16 + li] =
            make_float4(v0 - ls, v1 - ls, v2 - ls, v3 - ls);
}

extern "C" void kernel_launch(void* const* d_in, const int* in_sizes, int n_in,
                              void* d_out, int out_size, void* d_ws, size_t ws_size,
                              hipStream_t stream) {
    const float* x  = (const float*)d_in[0];
    const float* W1 = (const float*)d_in[1];
    const float* b1 = (const float*)d_in[2];
    const float* W2 = (const float*)d_in[3];
    const float* b2 = (const float*)d_in[4];
    const int* edge = (const int*)d_in[5];
    const int* src = edge;
    const int* dst = edge + N_EDGES;
    float* out = (float*)d_out;

    char* ws = (char*)d_ws;
    int*           bcnt  = (int*)(ws + 0);             //     1,564
    int*           boffs = (int*)(ws + 2048);          //     1,568
    int*           bcur  = (int*)(ws + 4096);          //     1,564
    float*         dinv  = (float*)(ws + 6144);        //   400,384 (MROWS)
    int*           rowp  = (int*)(ws + 406528);        //   400,000
    int*           rend  = (int*)(ws + 806528);        //   400,000
    int*           srcs  = (int*)(ws + 1206528);       // 9,700,000 (padded CSR)
    unsigned*      pairs = (unsigned*)(ws + 10906624); // 6,400,000
    short*         w1h   = (short*)(ws + 17306624);    //    32,768
    short*         w2h   = (short*)(ws + 17339392);    //    16,384
    unsigned char* y1f   = (unsigned char*)(ws + 17356800); // 12,812,288 (MROWS*128 fp8)
    short*         h1b   = (short*)(ws + 30169088);    // 25,624,576 (MROWS*128 bf16)
    unsigned char* y2f   = (unsigned char*)(ws + 55793664); //  6,406,144 (MROWS*64 fp8)
    // ends ~62.2 MB

    // ---- zero the sentinel rows (ZROW = N_NODES) for padded gathers ----
    hipMemsetAsync(y1f + (size_t)N_NODES * 128, 0, 128, stream);
    hipMemsetAsync(y2f + (size_t)N_NODES * 64, 0, 64, stream);

    // ---- CSR build: bucket histogram -> scan -> scatter -> padded bucket fill ----
    hipMemsetAsync(bcnt, 0, NB * sizeof(int), stream);
    bucket_count<<<512, 256, 0, stream>>>(dst, bcnt);
    bucket_scan<<<1, 512, 0, stream>>>(bcnt, boffs, bcur);
    bucket_scatter<<<(N_EDGES + CH - 1) / CH, 256, 0, stream>>>(src, dst, bcur, pairs);
    csr_fill_bucket<<<NB, 256, 0, stream>>>(pairs, boffs, rowp, rend, dinv, srcs);

    // ---- weight conversion ----
    convert_w<<<(128 * 128 + 64 * 128 + 255) / 256, 256, 0, stream>>>(W1, W2, w1h, w2h);

    // ---- layer 1 ----
    gemm1_mfma<<<MROWS / 128, 512, 0, stream>>>(x, w1h, dinv, y1f);
    agg_relu<<<(N_NODES + 3) / 4, 256, 0, stream>>>(rowp, rend, srcs, y1f, dinv, b1, h1b);

    // ---- layer 2 ----
    gemm2_mfma<<<MROWS / 128, 512, 0, stream>>>(h1b, w2h, dinv, y2f);
    agg_lsm<<<(N_NODES + 3) / 4, 256, 0, stream>>>(rowp, rend, srcs, y2f, dinv, b2, out);
}

// Round 13
// 271.791 us; speedup vs baseline: 1.3066x; 1.0769x over previous
//
#include <hip/hip_runtime.h>
#include <math.h>

#define N_NODES 100000
#define N_EDGES 1600000
#define NB 391              // dst buckets (d>>8), 256 nodes each
#define MROWS 100096        // 782*128, padded row count for guard-free tiles
#define CH 3200             // edges per bucket_scatter block -> 500 blocks
#define ZROW N_NODES        // sentinel zero row for edge-list padding

typedef __attribute__((ext_vector_type(8))) short short8;  // 8 bf16 = 4 VGPRs
typedef __attribute__((ext_vector_type(4))) float f32x4;
typedef __attribute__((ext_vector_type(2))) float f32x2;

__device__ __forceinline__ short f2b(float f) {            // fp32 -> bf16 RNE
    unsigned u = __float_as_uint(f);
    unsigned r = (u + 0x7FFFu + ((u >> 16) & 1u)) >> 16;
    return (short)r;
}
__device__ __forceinline__ unsigned pk2(float a, float b) {
    return (unsigned)(unsigned short)f2b(a) | ((unsigned)(unsigned short)f2b(b) << 16);
}
// f32 -> fp8 e4m3 (OCP), single byte
__device__ __forceinline__ unsigned char f2q(float v) {
    return (unsigned char)(__builtin_amdgcn_cvt_pk_fp8_f32(v, 0.f, 0, false) & 0xFF);
}
// accumulate 4 fp8 (one uint) into a[0..3]
__device__ __forceinline__ void acc4(float* a, unsigned u) {
    f32x2 lo = __builtin_amdgcn_cvt_pk_f32_fp8((int)u, false);
    f32x2 hi = __builtin_amdgcn_cvt_pk_f32_fp8((int)u, true);
    a[0] += lo[0]; a[1] += lo[1]; a[2] += hi[0]; a[3] += hi[1];
}

// pack 8 fp32 -> 8 bf16 (truncate; 1 v_perm per 2 elems)
__device__ __forceinline__ short8 pack8t(const float* __restrict__ p) {
    float4 v0 = ((const float4*)p)[0];
    float4 v1 = ((const float4*)p)[1];
    union { unsigned u[4]; short8 s; } r;
    r.u[0] = __builtin_amdgcn_perm(__float_as_uint(v0.y), __float_as_uint(v0.x), 0x07060302u);
    r.u[1] = __builtin_amdgcn_perm(__float_as_uint(v0.w), __float_as_uint(v0.z), 0x07060302u);
    r.u[2] = __builtin_amdgcn_perm(__float_as_uint(v1.y), __float_as_uint(v1.x), 0x07060302u);
    r.u[3] = __builtin_amdgcn_perm(__float_as_uint(v1.w), __float_as_uint(v1.z), 0x07060302u);
    return r.s;
}

// ---------- bucket histogram (LDS-staged) ----------
__global__ __launch_bounds__(256) void bucket_count(const int* __restrict__ dst,
                                                    int* __restrict__ bcnt) {
    __shared__ int h[NB];
    int t = threadIdx.x;
    for (int i = t; i < NB; i += 256) h[i] = 0;
    __syncthreads();
    for (int e = blockIdx.x * 256 + t; e < N_EDGES; e += gridDim.x * 256)
        atomicAdd(&h[dst[e] >> 8], 1);
    __syncthreads();
    for (int i = t; i < NB; i += 256)
        if (h[i]) atomicAdd(&bcnt[i], h[i]);
}

// ---------- bucket-level exclusive scan (one block) ----------
__global__ __launch_bounds__(512) void bucket_scan(const int* __restrict__ bcnt,
                                                   int* __restrict__ boffs,
                                                   int* __restrict__ bcur) {
    __shared__ int s[512];
    int t = threadIdx.x;
    int v = (t < NB) ? bcnt[t] : 0;
    s[t] = v;
    __syncthreads();
    for (int off = 1; off < 512; off <<= 1) {
        int u = (t >= off) ? s[t - off] : 0;
        __syncthreads();
        s[t] += u;
        __syncthreads();
    }
    if (t < NB) {
        int ex = s[t] - v;
        boffs[t] = ex;
        bcur[t] = ex;
    }
    if (t == 0) boffs[NB] = N_EDGES;
}

// ---------- scatter edges into bucket-grouped packed list ----------
// packed word: (d&255)<<24 | src   (src < 2^24)
__global__ __launch_bounds__(256) void bucket_scatter(const int* __restrict__ src,
                                                      const int* __restrict__ dst,
                                                      int* __restrict__ bcur,
                                                      unsigned* __restrict__ pairs) {
    __shared__ unsigned lw[CH];
    __shared__ short lb[CH];
    __shared__ int cnt[NB];
    __shared__ int lstart[NB];
    int t = threadIdx.x;
    int e0 = blockIdx.x * CH;
    int n = min(CH, N_EDGES - e0);
    for (int i = t; i < NB; i += 256) cnt[i] = 0;
    __syncthreads();
    for (int i = t; i < n; i += 256) {
        int s = src[e0 + i], d = dst[e0 + i];
        lw[i] = ((unsigned)(d & 255) << 24) | (unsigned)s;
        int b = d >> 8;
        lb[i] = (short)b;
        atomicAdd(&cnt[b], 1);
    }
    __syncthreads();
    for (int b = t; b < NB; b += 256) {
        int c = cnt[b];
        lstart[b] = c ? atomicAdd(&bcur[b], c) : 0;
        cnt[b] = 0;  // reuse as local cursor
    }
    __syncthreads();
    for (int i = t; i < n; i += 256) {
        int b = lb[i];
        int lo = atomicAdd(&cnt[b], 1);
        pairs[lstart[b] + lo] = lw[i];
    }
}

// ---------- bucket-local CSR fill with 16-padding; derives rinfo/dinv ----------
__global__ __launch_bounds__(256) void csr_fill_bucket(const unsigned* __restrict__ pairs,
                                                       const int* __restrict__ boffs,
                                                       int2* __restrict__ rinfo,
                                                       float* __restrict__ dinv,
                                                       int* __restrict__ srcs) {
    __shared__ int lcnt[256];
    __shared__ int ls[256];
    int t = threadIdx.x, b = blockIdx.x, base = b << 8;
    lcnt[t] = 0;
    __syncthreads();
    int lo_e = boffs[b], hi_e = boffs[b + 1];
    for (int i = lo_e + t; i < hi_e; i += 256)
        atomicAdd(&lcnt[pairs[i] >> 24], 1);
    __syncthreads();
    int c = lcnt[t];
    int cpad = (c + 15) & ~15;        // pad each node's list to multiple of 16
    ls[t] = cpad;
    __syncthreads();
    for (int off = 1; off < 256; off <<= 1) {
        int u = (t >= off) ? ls[t - off] : 0;
        __syncthreads();
        ls[t] += u;
        __syncthreads();
    }
    int pbase = ((lo_e + 15) & ~15) + b * 4096;  // 16-aligned padded bucket base
    int rp = pbase + ls[t] - cpad;
    int node = base + t;
    if (node < N_NODES) {
        rinfo[node] = make_int2(rp, rp + cpad);
        dinv[node] = rsqrtf((float)(c + 1));
    }
    __syncthreads();
    lcnt[t] = rp;                      // reuse as global cursor
    __syncthreads();
    for (int i = lo_e + t; i < hi_e; i += 256) {
        unsigned p = pairs[i];
        int li = p >> 24;
        int pos = atomicAdd(&lcnt[li], 1);
        srcs[pos] = (int)(p & 0xFFFFFFu);
    }
    __syncthreads();
    // pad fill: thread t pads its own node with the zero-row sentinel
    for (int i = lcnt[t], stop = rp + cpad; i < stop; ++i) srcs[i] = ZROW;
}

// ---------- W1 [128][128] + W2 [128][64] fp32 -> Wt [N][128] bf16 ----------
__global__ __launch_bounds__(256) void convert_w(const float* __restrict__ W1,
                                                 const float* __restrict__ W2,
                                                 short* __restrict__ w1h,
                                                 short* __restrict__ w2h) {
    int id = blockIdx.x * 256 + threadIdx.x;
    if (id < 128 * 128) {
        int n = id >> 7, k = id & 127;
        w1h[id] = f2b(W1[k * 128 + n]);
    } else if (id < 128 * 128 + 64 * 128) {
        int j = id - 128 * 128;
        int n = j >> 7, k = j & 127;
        w2h[j] = f2b(W2[k * 64 + n]);
    }
}

// ---------- layer-1 GEMM: Y1 = fp8((X @ W1) * dinv); W in LDS, 16 rows/wave ----------
__global__ __launch_bounds__(512) void gemm1_mfma(const float* __restrict__ X,
                                                  const short* __restrict__ Wt,
                                                  const float* __restrict__ dinv,
                                                  unsigned char* __restrict__ Yf) {
    __shared__ short Ws[128 * 128];   // 32 KB
    const int t = threadIdx.x;
    for (int i = t * 8; i < 128 * 128; i += 512 * 8)
        *(short8*)(Ws + i) = *(const short8*)(Wt + i);
    __syncthreads();

    const int w = t >> 6, lane = t & 63;
    const int m = lane & 15, q = lane >> 4;
    const int r0 = blockIdx.x * 128 + w * 16;
    const int ra = min(r0 + m, N_NODES - 1);

    f32x4 acc[8];
#pragma unroll
    for (int c = 0; c < 8; ++c) acc[c] = (f32x4)(0.f);

#pragma unroll
    for (int kk = 0; kk < 4; ++kk) {
        const int koff = kk * 32 + q * 8;
        short8 a = pack8t(X + (size_t)ra * 128 + koff);
#pragma unroll
        for (int c = 0; c < 8; ++c) {
            short8 bh = *(const short8*)(Ws + (c * 16 + m) * 128 + koff);
            acc[c] = __builtin_amdgcn_mfma_f32_16x16x32_bf16(a, bh, acc[c], 0, 0, 0);
        }
    }

    // C/D layout: col=lane&15, row=q*4+reg  [verified m89/m91]
    const int rb0 = r0 + q * 4;
    f32x4 dv = *(const f32x4*)(dinv + rb0);
#pragma unroll
    for (int c = 0; c < 8; ++c) {
        const int col = c * 16 + m;
#pragma unroll
        for (int r = 0; r < 4; ++r) {
            int row = rb0 + r;
            if (row < N_NODES) Yf[(size_t)row * 128 + col] = f2q(acc[c][r] * dv[r]);
        }
    }
}

// ---------- layer-2 GEMM: Y2 = fp8((H @ W2) * dinv); W in LDS, 16 rows/wave ----------
__global__ __launch_bounds__(512) void gemm2_mfma(const short* __restrict__ H,
                                                  const short* __restrict__ Wt,
                                                  const float* __restrict__ dinv,
                                                  unsigned char* __restrict__ Yf) {
    __shared__ short Ws[64 * 128];    // 16 KB
    const int t = threadIdx.x;
    for (int i = t * 8; i < 64 * 128; i += 512 * 8)
        *(short8*)(Ws + i) = *(const short8*)(Wt + i);
    __syncthreads();

    const int w = t >> 6, lane = t & 63;
    const int m = lane & 15, q = lane >> 4;
    const int r0 = blockIdx.x * 128 + w * 16;

    f32x4 acc[4];
#pragma unroll
    for (int c = 0; c < 4; ++c) acc[c] = (f32x4)(0.f);

#pragma unroll
    for (int kk = 0; kk < 4; ++kk) {
        const int koff = kk * 32 + q * 8;
        short8 a = *(const short8*)(H + (size_t)(r0 + m) * 128 + koff);
#pragma unroll
        for (int c = 0; c < 4; ++c) {
            short8 bh = *(const short8*)(Ws + (c * 16 + m) * 128 + koff);
            acc[c] = __builtin_amdgcn_mfma_f32_16x16x32_bf16(a, bh, acc[c], 0, 0, 0);
        }
    }

    const int rb0 = r0 + q * 4;
    f32x4 dv = *(const f32x4*)(dinv + rb0);
#pragma unroll
    for (int c = 0; c < 4; ++c) {
        const int col = c * 16 + m;
#pragma unroll
        for (int r = 0; r < 4; ++r) {
            int row = rb0 + r;
            if (row < N_NODES) Yf[(size_t)row * 64 + col] = f2q(acc[c][r] * dv[r]);
        }
    }
}

// ---------- CSR aggregation, K=128 fp8: half-wave/edge, 16-edge pipeline ----------
__global__ __launch_bounds__(256) void agg_relu(const int2* __restrict__ rinfo,
                                                const int* __restrict__ srcs,
                                                const unsigned char* __restrict__ Yf,
                                                const float* __restrict__ dinv,
                                                const float* __restrict__ b,
                                                short* __restrict__ Hb) {
    int t = threadIdx.x;
    int lane = t & 63, w = t >> 6;
    int half = lane >> 5, li = lane & 31;     // 2 groups of 32 lanes
    int d = blockIdx.x * 4 + w;
    if (d >= N_NODES) return;
    const unsigned fo = (unsigned)(li << 2);
    int2 ri = rinfo[d];
    unsigned selfu = *(const unsigned*)(Yf + (((unsigned)d << 7) + fo));
    float a[4] = {0.f, 0.f, 0.f, 0.f};
    for (int e = ri.x; e < ri.y; e += 16) {   // uniform: list padded to x16
        const int* sp = srcs + e + 8 * half;  // this half's 8 edges
        uint4 s0 = *(const uint4*)sp;
        uint4 s1 = *(const uint4*)(sp + 4);
        unsigned g0 = *(const unsigned*)(Yf + (((unsigned)s0.x << 7) + fo));
        unsigned g1 = *(const unsigned*)(Yf + (((unsigned)s0.y << 7) + fo));
        unsigned g2 = *(const unsigned*)(Yf + (((unsigned)s0.z << 7) + fo));
        unsigned g3 = *(const unsigned*)(Yf + (((unsigned)s0.w << 7) + fo));
        unsigned g4 = *(const unsigned*)(Yf + (((unsigned)s1.x << 7) + fo));
        unsigned g5 = *(const unsigned*)(Yf + (((unsigned)s1.y << 7) + fo));
        unsigned g6 = *(const unsigned*)(Yf + (((unsigned)s1.z << 7) + fo));
        unsigned g7 = *(const unsigned*)(Yf + (((unsigned)s1.w << 7) + fo));
        acc4(a, g0); acc4(a, g1); acc4(a, g2); acc4(a, g3);
        acc4(a, g4); acc4(a, g5); acc4(a, g6); acc4(a, g7);
    }
    if (!half) acc4(a, selfu);                // self loop, counted once
#pragma unroll
    for (int i = 0; i < 4; ++i) a[i] += __shfl_xor(a[i], 32);
    if (!half) {                              // feats 4*li .. 4*li+3
        float sc = dinv[d];
        float4 bb = ((const float4*)b)[li];
        float v0 = fmaxf(sc * a[0] + bb.x, 0.f);
        float v1 = fmaxf(sc * a[1] + bb.y, 0.f);
        float v2 = fmaxf(sc * a[2] + bb.z, 0.f);
        float v3 = fmaxf(sc * a[3] + bb.w, 0.f);
        ((uint2*)Hb)[(size_t)d * 32 + li] = make_uint2(pk2(v0, v1), pk2(v2, v3));
    }
}

// ---------- CSR aggregation, K=64 fp8: quarter-wave/edge, 16-edge pipeline ----------
__global__ __launch_bounds__(256) void agg_lsm(const int2* __restrict__ rinfo,
                                               const int* __restrict__ srcs,
                                               const unsigned char* __restrict__ Yf,
                                               const float* __restrict__ dinv,
                                               const float* __restrict__ b,
                                               float* __restrict__ out) {
    int t = threadIdx.x;
    int lane = t & 63, w = t >> 6;
    int gi = lane >> 4, li = lane & 15;       // 4 groups of 16 lanes
    int d = blockIdx.x * 4 + w;
    if (d >= N_NODES) return;
    const unsigned fo = (unsigned)(li << 2);
    int2 ri = rinfo[d];
    unsigned selfu = *(const unsigned*)(Yf + (((unsigned)d << 6) + fo));
    float a[4] = {0.f, 0.f, 0.f, 0.f};
    for (int e = ri.x; e < ri.y; e += 16) {   // uniform: list padded to x16
        uint4 sv = *(const uint4*)(srcs + e + 4 * gi);  // this group's 4 edges
        unsigned g0 = *(const unsigned*)(Yf + (((unsigned)sv.x << 6) + fo));
        unsigned g1 = *(const unsigned*)(Yf + (((unsigned)sv.y << 6) + fo));
        unsigned g2 = *(const unsigned*)(Yf + (((unsigned)sv.z << 6) + fo));
        unsigned g3 = *(const unsigned*)(Yf + (((unsigned)sv.w << 6) + fo));
        acc4(a, g0); acc4(a, g1); acc4(a, g2); acc4(a, g3);
    }
    if (gi == 0) acc4(a, selfu);              // self loop, counted once
#pragma unroll
    for (int i = 0; i < 4; ++i) {
        a[i] += __shfl_xor(a[i], 16);
        a[i] += __shfl_xor(a[i], 32);
    }
    float sc = dinv[d];
    float4 bb = ((const float4*)b)[li];
    float v0 = sc * a[0] + bb.x;
    float v1 = sc * a[1] + bb.y;
    float v2 = sc * a[2] + bb.z;
    float v3 = sc * a[3] + bb.w;
    float m = fmaxf(fmaxf(v0, v1), fmaxf(v2, v3));
#pragma unroll
    for (int o = 1; o <= 8; o <<= 1) m = fmaxf(m, __shfl_xor(m, o));
    float su = __expf(v0 - m) + __expf(v1 - m) + __expf(v2 - m) + __expf(v3 - m);
#pragma unroll
    for (int o = 1; o <= 8; o <<= 1) su += __shfl_xor(su, o);
    float ls = m + logf(su);
    if (gi == 0)
        ((float4*)out)[(size_t)d * 16 + li] =
            make_float4(v0 - ls, v1 - ls, v2 - ls, v3 - ls);
}

extern "C" void kernel_launch(void* const* d_in, const int* in_sizes, int n_in,
                              void* d_out, int out_size, void* d_ws, size_t ws_size,
                              hipStream_t stream) {
    const float* x  = (const float*)d_in[0];
    const float* W1 = (const float*)d_in[1];
    const float* b1 = (const float*)d_in[2];
    const float* W2 = (const float*)d_in[3];
    const float* b2 = (const float*)d_in[4];
    const int* edge = (const int*)d_in[5];
    const int* src = edge;
    const int* dst = edge + N_EDGES;
    float* out = (float*)d_out;

    char* ws = (char*)d_ws;
    int*           bcnt  = (int*)(ws + 0);             //     1,564
    int*           boffs = (int*)(ws + 2048);          //     1,568
    int*           bcur  = (int*)(ws + 4096);          //     1,564
    float*         dinv  = (float*)(ws + 6144);        //   400,384 (MROWS)
    int2*          rinfo = (int2*)(ws + 406528);       //   800,000
    int*           srcs  = (int*)(ws + 1206528);       // 12,806,144 (16-padded CSR)
    unsigned*      pairs = (unsigned*)(ws + 14012672); //  6,400,000
    short*         w1h   = (short*)(ws + 20412672);    //     32,768
    short*         w2h   = (short*)(ws + 20445440);    //     16,384
    unsigned char* y1f   = (unsigned char*)(ws + 20461824); // 12,812,288 (MROWS*128 fp8)
    short*         h1b   = (short*)(ws + 33274112);    // 25,624,576 (MROWS*128 bf16)
    unsigned char* y2f   = (unsigned char*)(ws + 58898688); //  6,406,144 (MROWS*64 fp8)
    // ends ~65.3 MB

    // ---- zero the sentinel rows (ZROW = N_NODES) for padded gathers ----
    hipMemsetAsync(y1f + (size_t)N_NODES * 128, 0, 128, stream);
    hipMemsetAsync(y2f + (size_t)N_NODES * 64, 0, 64, stream);

    // ---- CSR build: bucket histogram -> scan -> scatter -> padded bucket fill ----
    hipMemsetAsync(bcnt, 0, NB * sizeof(int), stream);
    bucket_count<<<512, 256, 0, stream>>>(dst, bcnt);
    bucket_scan<<<1, 512, 0, stream>>>(bcnt, boffs, bcur);
    bucket_scatter<<<(N_EDGES + CH - 1) / CH, 256, 0, stream>>>(src, dst, bcur, pairs);
    csr_fill_bucket<<<NB, 256, 0, stream>>>(pairs, boffs, rinfo, dinv, srcs);

    // ---- weight conversion ----
    convert_w<<<(128 * 128 + 64 * 128 + 255) / 256, 256, 0, stream>>>(W1, W2, w1h, w2h);

    // ---- layer 1 ----
    gemm1_mfma<<<MROWS / 128, 512, 0, stream>>>(x, w1h, dinv, y1f);
    agg_relu<<<(N_NODES + 3) / 4, 256, 0, stream>>>(rinfo, srcs, y1f, dinv, b1, h1b);

    // ---- layer 2 ----
    gemm2_mfma<<<MROWS / 128, 512, 0, stream>>>(h1b, w2h, dinv, y2f);
    agg_lsm<<<(N_NODES + 3) / 4, 256, 0, stream>>>(rinfo, srcs, y2f, dinv, b2, out);
}

// Round 14
// 268.513 us; speedup vs baseline: 1.3225x; 1.0122x over previous
//
#include <hip/hip_runtime.h>
#include <math.h>

#define N_NODES 100000
#define N_EDGES 1600000
#define NB 391              // dst buckets (d>>8), 256 nodes each
#define MROWS 100096        // 782*128, padded row count for guard-free tiles
#define CH 3200             // edges per bucket_scatter block -> 500 blocks
#define ZROW N_NODES        // sentinel zero row for edge-list padding

typedef __attribute__((ext_vector_type(8))) short short8;  // 8 bf16 = 4 VGPRs
typedef __attribute__((ext_vector_type(4))) float f32x4;
typedef __attribute__((ext_vector_type(2))) float f32x2;

__device__ __forceinline__ short f2b(float f) {            // fp32 -> bf16 RNE
    unsigned u = __float_as_uint(f);
    unsigned r = (u + 0x7FFFu + ((u >> 16) & 1u)) >> 16;
    return (short)r;
}
__device__ __forceinline__ unsigned pk2(float a, float b) {
    return (unsigned)(unsigned short)f2b(a) | ((unsigned)(unsigned short)f2b(b) << 16);
}
// f32 -> fp8 e4m3 (OCP), single byte
__device__ __forceinline__ unsigned char f2q(float v) {
    return (unsigned char)(__builtin_amdgcn_cvt_pk_fp8_f32(v, 0.f, 0, false) & 0xFF);
}
// accumulate 4 fp8 (one uint) into a[0..3]
__device__ __forceinline__ void acc4(float* a, unsigned u) {
    f32x2 lo = __builtin_amdgcn_cvt_pk_f32_fp8((int)u, false);
    f32x2 hi = __builtin_amdgcn_cvt_pk_f32_fp8((int)u, true);
    a[0] += lo[0]; a[1] += lo[1]; a[2] += hi[0]; a[3] += hi[1];
}

// pack 8 fp32 -> 8 bf16 (truncate; 1 v_perm per 2 elems)
__device__ __forceinline__ short8 pack8t(const float* __restrict__ p) {
    float4 v0 = ((const float4*)p)[0];
    float4 v1 = ((const float4*)p)[1];
    union { unsigned u[4]; short8 s; } r;
    r.u[0] = __builtin_amdgcn_perm(__float_as_uint(v0.y), __float_as_uint(v0.x), 0x07060302u);
    r.u[1] = __builtin_amdgcn_perm(__float_as_uint(v0.w), __float_as_uint(v0.z), 0x07060302u);
    r.u[2] = __builtin_amdgcn_perm(__float_as_uint(v1.y), __float_as_uint(v1.x), 0x07060302u);
    r.u[3] = __builtin_amdgcn_perm(__float_as_uint(v1.w), __float_as_uint(v1.z), 0x07060302u);
    return r.s;
}

// ---------- one-shot init: bcnt + sentinel zero rows (replaces 3 memsets) ----------
__global__ __launch_bounds__(512) void init_misc(int* __restrict__ bcnt,
                                                 unsigned* __restrict__ y1s,
                                                 unsigned* __restrict__ y2s) {
    int t = threadIdx.x;
    if (t < NB) bcnt[t] = 0;
    if (t < 32) y1s[t] = 0;   // 128 B sentinel row (y1f row ZROW)
    if (t < 16) y2s[t] = 0;   // 64 B sentinel row (y2f row ZROW)
}

// ---------- bucket histogram (LDS-staged) ----------
__global__ __launch_bounds__(256) void bucket_count(const int* __restrict__ dst,
                                                    int* __restrict__ bcnt) {
    __shared__ int h[NB];
    int t = threadIdx.x;
    for (int i = t; i < NB; i += 256) h[i] = 0;
    __syncthreads();
    for (int e = blockIdx.x * 256 + t; e < N_EDGES; e += gridDim.x * 256)
        atomicAdd(&h[dst[e] >> 8], 1);
    __syncthreads();
    for (int i = t; i < NB; i += 256)
        if (h[i]) atomicAdd(&bcnt[i], h[i]);
}

// ---------- bucket-level exclusive scan (one block) ----------
__global__ __launch_bounds__(512) void bucket_scan(const int* __restrict__ bcnt,
                                                   int* __restrict__ boffs,
                                                   int* __restrict__ bcur) {
    __shared__ int s[512];
    int t = threadIdx.x;
    int v = (t < NB) ? bcnt[t] : 0;
    s[t] = v;
    __syncthreads();
    for (int off = 1; off < 512; off <<= 1) {
        int u = (t >= off) ? s[t - off] : 0;
        __syncthreads();
        s[t] += u;
        __syncthreads();
    }
    if (t < NB) {
        int ex = s[t] - v;
        boffs[t] = ex;
        bcur[t] = ex;
    }
    if (t == 0) boffs[NB] = N_EDGES;
}

// ---------- scatter edges into bucket-grouped packed list ----------
// packed word: (d&255)<<24 | src   (src < 2^24)
__global__ __launch_bounds__(256) void bucket_scatter(const int* __restrict__ src,
                                                      const int* __restrict__ dst,
                                                      int* __restrict__ bcur,
                                                      unsigned* __restrict__ pairs) {
    __shared__ unsigned lw[CH];
    __shared__ short lb[CH];
    __shared__ int cnt[NB];
    __shared__ int lstart[NB];
    int t = threadIdx.x;
    int e0 = blockIdx.x * CH;
    int n = min(CH, N_EDGES - e0);
    for (int i = t; i < NB; i += 256) cnt[i] = 0;
    __syncthreads();
    for (int i = t; i < n; i += 256) {
        int s = src[e0 + i], d = dst[e0 + i];
        lw[i] = ((unsigned)(d & 255) << 24) | (unsigned)s;
        int b = d >> 8;
        lb[i] = (short)b;
        atomicAdd(&cnt[b], 1);
    }
    __syncthreads();
    for (int b = t; b < NB; b += 256) {
        int c = cnt[b];
        lstart[b] = c ? atomicAdd(&bcur[b], c) : 0;
        cnt[b] = 0;  // reuse as local cursor
    }
    __syncthreads();
    for (int i = t; i < n; i += 256) {
        int b = lb[i];
        int lo = atomicAdd(&cnt[b], 1);
        pairs[lstart[b] + lo] = lw[i];
    }
}

// ---------- bucket-local CSR fill with 8-padding; derives rinfo/dinv ----------
__global__ __launch_bounds__(256) void csr_fill_bucket(const unsigned* __restrict__ pairs,
                                                       const int* __restrict__ boffs,
                                                       int2* __restrict__ rinfo,
                                                       float* __restrict__ dinv,
                                                       int* __restrict__ srcs) {
    __shared__ int lcnt[256];
    __shared__ int ls[256];
    int t = threadIdx.x, b = blockIdx.x, base = b << 8;
    lcnt[t] = 0;
    __syncthreads();
    int lo_e = boffs[b], hi_e = boffs[b + 1];
    for (int i = lo_e + t; i < hi_e; i += 256)
        atomicAdd(&lcnt[pairs[i] >> 24], 1);
    __syncthreads();
    int c = lcnt[t];
    int cpad = (c + 7) & ~7;          // pad each node's list to multiple of 8
    ls[t] = cpad;
    __syncthreads();
    for (int off = 1; off < 256; off <<= 1) {
        int u = (t >= off) ? ls[t - off] : 0;
        __syncthreads();
        ls[t] += u;
        __syncthreads();
    }
    int pbase = ((lo_e + 7) & ~7) + b * 2048;  // 8-aligned padded bucket base
    int rp = pbase + ls[t] - cpad;
    int node = base + t;
    if (node < N_NODES) {
        rinfo[node] = make_int2(rp, rp + cpad);
        dinv[node] = rsqrtf((float)(c + 1));
    }
    __syncthreads();
    lcnt[t] = rp;                      // reuse as global cursor
    __syncthreads();
    for (int i = lo_e + t; i < hi_e; i += 256) {
        unsigned p = pairs[i];
        int li = p >> 24;
        int pos = atomicAdd(&lcnt[li], 1);
        srcs[pos] = (int)(p & 0xFFFFFFu);
    }
    __syncthreads();
    // pad fill: thread t pads its own node with the zero-row sentinel
    for (int i = lcnt[t], stop = rp + cpad; i < stop; ++i) srcs[i] = ZROW;
}

// ---------- W1 [128][128] + W2 [128][64] fp32 -> Wt [N][128] bf16 ----------
__global__ __launch_bounds__(256) void convert_w(const float* __restrict__ W1,
                                                 const float* __restrict__ W2,
                                                 short* __restrict__ w1h,
                                                 short* __restrict__ w2h) {
    int id = blockIdx.x * 256 + threadIdx.x;
    if (id < 128 * 128) {
        int n = id >> 7, k = id & 127;
        w1h[id] = f2b(W1[k * 128 + n]);
    } else if (id < 128 * 128 + 64 * 128) {
        int j = id - 128 * 128;
        int n = j >> 7, k = j & 127;
        w2h[j] = f2b(W2[k * 64 + n]);
    }
}

// ---------- layer-1 GEMM: Y1 = fp8((X @ W1) * dinv); W in LDS, 16 rows/wave ----------
__global__ __launch_bounds__(512) void gemm1_mfma(const float* __restrict__ X,
                                                  const short* __restrict__ Wt,
                                                  const float* __restrict__ dinv,
                                                  unsigned char* __restrict__ Yf) {
    __shared__ short Ws[128 * 128];   // 32 KB
    const int t = threadIdx.x;
    for (int i = t * 8; i < 128 * 128; i += 512 * 8)
        *(short8*)(Ws + i) = *(const short8*)(Wt + i);
    __syncthreads();

    const int w = t >> 6, lane = t & 63;
    const int m = lane & 15, q = lane >> 4;
    const int r0 = blockIdx.x * 128 + w * 16;
    const int ra = min(r0 + m, N_NODES - 1);

    f32x4 acc[8];
#pragma unroll
    for (int c = 0; c < 8; ++c) acc[c] = (f32x4)(0.f);

#pragma unroll
    for (int kk = 0; kk < 4; ++kk) {
        const int koff = kk * 32 + q * 8;
        short8 a = pack8t(X + (size_t)ra * 128 + koff);
#pragma unroll
        for (int c = 0; c < 8; ++c) {
            short8 bh = *(const short8*)(Ws + (c * 16 + m) * 128 + koff);
            acc[c] = __builtin_amdgcn_mfma_f32_16x16x32_bf16(a, bh, acc[c], 0, 0, 0);
        }
    }

    // C/D layout: col=lane&15, row=q*4+reg  [verified m89/m91]
    const int rb0 = r0 + q * 4;
    f32x4 dv = *(const f32x4*)(dinv + rb0);
#pragma unroll
    for (int c = 0; c < 8; ++c) {
        const int col = c * 16 + m;
#pragma unroll
        for (int r = 0; r < 4; ++r) {
            int row = rb0 + r;
            if (row < N_NODES) Yf[(size_t)row * 128 + col] = f2q(acc[c][r] * dv[r]);
        }
    }
}

// ---------- layer-2 GEMM: Y2 = fp8((H @ W2) * dinv); W in LDS, 16 rows/wave ----------
__global__ __launch_bounds__(512) void gemm2_mfma(const short* __restrict__ H,
                                                  const short* __restrict__ Wt,
                                                  const float* __restrict__ dinv,
                                                  unsigned char* __restrict__ Yf) {
    __shared__ short Ws[64 * 128];    // 16 KB
    const int t = threadIdx.x;
    for (int i = t * 8; i < 64 * 128; i += 512 * 8)
        *(short8*)(Ws + i) = *(const short8*)(Wt + i);
    __syncthreads();

    const int w = t >> 6, lane = t & 63;
    const int m = lane & 15, q = lane >> 4;
    const int r0 = blockIdx.x * 128 + w * 16;

    f32x4 acc[4];
#pragma unroll
    for (int c = 0; c < 4; ++c) acc[c] = (f32x4)(0.f);

#pragma unroll
    for (int kk = 0; kk < 4; ++kk) {
        const int koff = kk * 32 + q * 8;
        short8 a = *(const short8*)(H + (size_t)(r0 + m) * 128 + koff);
#pragma unroll
        for (int c = 0; c < 4; ++c) {
            short8 bh = *(const short8*)(Ws + (c * 16 + m) * 128 + koff);
            acc[c] = __builtin_amdgcn_mfma_f32_16x16x32_bf16(a, bh, acc[c], 0, 0, 0);
        }
    }

    const int rb0 = r0 + q * 4;
    f32x4 dv = *(const f32x4*)(dinv + rb0);
#pragma unroll
    for (int c = 0; c < 4; ++c) {
        const int col = c * 16 + m;
#pragma unroll
        for (int r = 0; r < 4; ++r) {
            int row = rb0 + r;
            if (row < N_NODES) Yf[(size_t)row * 64 + col] = f2q(acc[c][r] * dv[r]);
        }
    }
}

// ---------- CSR aggregation, K=128 fp8: 2 nodes/wave interleaved, pad-8 ----------
__global__ __launch_bounds__(256) void agg_relu(const int2* __restrict__ rinfo,
                                                const int* __restrict__ srcs,
                                                const unsigned char* __restrict__ Yf,
                                                const float* __restrict__ dinv,
                                                const float* __restrict__ b,
                                                short* __restrict__ Hb) {
    int t = threadIdx.x;
    int lane = t & 63, w = t >> 6;
    int half = lane >> 5, li = lane & 31;     // 2 halves of 32 lanes (one row each)
    int d0 = blockIdx.x * 8 + 2 * w;          // N_NODES % 8 == 0: no bounds check
    int d1 = d0 + 1;
    const unsigned fo = (unsigned)(li << 2);
    int2 r0 = rinfo[d0], r1 = rinfo[d1];
    float a0[4] = {0.f, 0.f, 0.f, 0.f};
    float a1[4] = {0.f, 0.f, 0.f, 0.f};
    {   // self loops: half 0 -> d0, half 1 -> d1 (single load, counted once)
        unsigned dh = half ? (unsigned)d1 : (unsigned)d0;
        unsigned su = *(const unsigned*)(Yf + ((dh << 7) + fo));
        if (!half) acc4(a0, su); else acc4(a1, su);
    }
    int e0 = r0.x, n0 = r0.y, e1 = r1.x, n1 = r1.y;
    while (true) {                             // two independent chains in flight
        bool c0 = e0 < n0, c1 = e1 < n1;       // wave-uniform: scalar branches
        if (!(c0 | c1)) break;
        if (c0) {                              // 8 edges of d0 (4 per half)
            uint4 s = *(const uint4*)(srcs + e0 + 4 * half);
            unsigned g0 = *(const unsigned*)(Yf + (((unsigned)s.x << 7) + fo));
            unsigned g1 = *(const unsigned*)(Yf + (((unsigned)s.y << 7) + fo));
            unsigned g2 = *(const unsigned*)(Yf + (((unsigned)s.z << 7) + fo));
            unsigned g3 = *(const unsigned*)(Yf + (((unsigned)s.w << 7) + fo));
            acc4(a0, g0); acc4(a0, g1); acc4(a0, g2); acc4(a0, g3);
            e0 += 8;
        }
        if (c1) {                              // 8 edges of d1
            uint4 s = *(const uint4*)(srcs + e1 + 4 * half);
            unsigned g0 = *(const unsigned*)(Yf + (((unsigned)s.x << 7) + fo));
            unsigned g1 = *(const unsigned*)(Yf + (((unsigned)s.y << 7) + fo));
            unsigned g2 = *(const unsigned*)(Yf + (((unsigned)s.z << 7) + fo));
            unsigned g3 = *(const unsigned*)(Yf + (((unsigned)s.w << 7) + fo));
            acc4(a1, g0); acc4(a1, g1); acc4(a1, g2); acc4(a1, g3);
            e1 += 8;
        }
    }
#pragma unroll
    for (int i = 0; i < 4; ++i) {
        a0[i] += __shfl_xor(a0[i], 32);
        a1[i] += __shfl_xor(a1[i], 32);
    }
    // epilogue: half 0 -> d0, half 1 -> d1 (cndmask select, full-wave store)
    int dd = half ? d1 : d0;
    float s0 = half ? a1[0] : a0[0];
    float s1 = half ? a1[1] : a0[1];
    float s2 = half ? a1[2] : a0[2];
    float s3 = half ? a1[3] : a0[3];
    float sc = dinv[dd];
    float4 bb = ((const float4*)b)[li];
    float v0 = fmaxf(sc * s0 + bb.x, 0.f);
    float v1 = fmaxf(sc * s1 + bb.y, 0.f);
    float v2 = fmaxf(sc * s2 + bb.z, 0.f);
    float v3 = fmaxf(sc * s3 + bb.w, 0.f);
    ((uint2*)Hb)[(size_t)dd * 32 + li] = make_uint2(pk2(v0, v1), pk2(v2, v3));
}

// ---------- CSR aggregation, K=64 fp8: 2 nodes/wave interleaved + log_softmax ----------
__global__ __launch_bounds__(256) void agg_lsm(const int2* __restrict__ rinfo,
                                               const int* __restrict__ srcs,
                                               const unsigned char* __restrict__ Yf,
                                               const float* __restrict__ dinv,
                                               const float* __restrict__ b,
                                               float* __restrict__ out) {
    int t = threadIdx.x;
    int lane = t & 63, w = t >> 6;
    int gi = lane >> 4, li = lane & 15;       // 4 groups of 16 lanes (one row each)
    int d0 = blockIdx.x * 8 + 2 * w;
    int d1 = d0 + 1;
    const unsigned fo = (unsigned)(li << 2);
    int2 r0 = rinfo[d0], r1 = rinfo[d1];
    float a0[4] = {0.f, 0.f, 0.f, 0.f};
    float a1[4] = {0.f, 0.f, 0.f, 0.f};
    {   // self loops: group 0 -> d0 into a0, group 1 -> d1 into a1
        unsigned dh = (gi == 1) ? (unsigned)d1 : (unsigned)d0;
        unsigned su = *(const unsigned*)(Yf + ((dh << 6) + fo));
        if (gi == 0) acc4(a0, su);
        else if (gi == 1) acc4(a1, su);
    }
    int e0 = r0.x, n0 = r0.y, e1 = r1.x, n1 = r1.y;
    while (true) {
        bool c0 = e0 < n0, c1 = e1 < n1;
        if (!(c0 | c1)) break;
        if (c0) {                              // 8 edges of d0 (2 per group)
            uint2 s = *(const uint2*)(srcs + e0 + 2 * gi);
            unsigned g0 = *(const unsigned*)(Yf + (((unsigned)s.x << 6) + fo));
            unsigned g1 = *(const unsigned*)(Yf + (((unsigned)s.y << 6) + fo));
            acc4(a0, g0); acc4(a0, g1);
            e0 += 8;
        }
        if (c1) {                              // 8 edges of d1
            uint2 s = *(const uint2*)(srcs + e1 + 2 * gi);
            unsigned g0 = *(const unsigned*)(Yf + (((unsigned)s.x << 6) + fo));
            unsigned g1 = *(const unsigned*)(Yf + (((unsigned)s.y << 6) + fo));
            acc4(a1, g0); acc4(a1, g1);
            e1 += 8;
        }
    }
    // merge the 4 groups -> all lanes hold totals
#pragma unroll
    for (int i = 0; i < 4; ++i) {
        a0[i] += __shfl_xor(a0[i], 16);
        a0[i] += __shfl_xor(a0[i], 32);
        a1[i] += __shfl_xor(a1[i], 16);
        a1[i] += __shfl_xor(a1[i], 32);
    }
    // groups 0,1 -> d0; groups 2,3 -> d1 (cndmask select)
    int gsel = gi >> 1;
    int dd = gsel ? d1 : d0;
    float s0 = gsel ? a1[0] : a0[0];
    float s1 = gsel ? a1[1] : a0[1];
    float s2 = gsel ? a1[2] : a0[2];
    float s3 = gsel ? a1[3] : a0[3];
    float sc = dinv[dd];
    float4 bb = ((const float4*)b)[li];
    float v0 = sc * s0 + bb.x;
    float v1 = sc * s1 + bb.y;
    float v2 = sc * s2 + bb.z;
    float v3 = sc * s3 + bb.w;
    float m = fmaxf(fmaxf(v0, v1), fmaxf(v2, v3));
#pragma unroll
    for (int o = 1; o <= 8; o <<= 1) m = fmaxf(m, __shfl_xor(m, o));
    float su = __expf(v0 - m) + __expf(v1 - m) + __expf(v2 - m) + __expf(v3 - m);
#pragma unroll
    for (int o = 1; o <= 8; o <<= 1) su += __shfl_xor(su, o);
    float ls = m + logf(su);
    if ((gi & 1) == 0)                          // groups 0 and 2 write their node
        ((float4*)out)[(size_t)dd * 16 + li] =
            make_float4(v0 - ls, v1 - ls, v2 - ls, v3 - ls);
}

extern "C" void kernel_launch(void* const* d_in, const int* in_sizes, int n_in,
                              void* d_out, int out_size, void* d_ws, size_t ws_size,
                              hipStream_t stream) {
    const float* x  = (const float*)d_in[0];
    const float* W1 = (const float*)d_in[1];
    const float* b1 = (const float*)d_in[2];
    const float* W2 = (const float*)d_in[3];
    const float* b2 = (const float*)d_in[4];
    const int* edge = (const int*)d_in[5];
    const int* src = edge;
    const int* dst = edge + N_EDGES;
    float* out = (float*)d_out;

    char* ws = (char*)d_ws;
    int*           bcnt  = (int*)(ws + 0);             //     1,564
    int*           boffs = (int*)(ws + 2048);          //     1,568
    int*           bcur  = (int*)(ws + 4096);          //     1,564
    float*         dinv  = (float*)(ws + 6144);        //   400,384 (MROWS)
    int2*          rinfo = (int2*)(ws + 406528);       //   800,000
    int*           srcs  = (int*)(ws + 1206528);       // 12,806,144 (8-padded CSR)
    unsigned*      pairs = (unsigned*)(ws + 14012672); //  6,400,000
    short*         w1h   = (short*)(ws + 20412672);    //     32,768
    short*         w2h   = (short*)(ws + 20445440);    //     16,384
    unsigned char* y1f   = (unsigned char*)(ws + 20461824); // 12,812,288 (MROWS*128 fp8)
    short*         h1b   = (short*)(ws + 33274112);    // 25,624,576 (MROWS*128 bf16)
    unsigned char* y2f   = (unsigned char*)(ws + 58898688); //  6,406,144 (MROWS*64 fp8)
    // ends ~65.3 MB

    // ---- one-dispatch init: bcnt zeros + both sentinel rows ----
    init_misc<<<1, 512, 0, stream>>>(bcnt,
                                     (unsigned*)(y1f + (size_t)N_NODES * 128),
                                     (unsigned*)(y2f + (size_t)N_NODES * 64));

    // ---- CSR build: bucket histogram -> scan -> scatter -> padded bucket fill ----
    bucket_count<<<512, 256, 0, stream>>>(dst, bcnt);
    bucket_scan<<<1, 512, 0, stream>>>(bcnt, boffs, bcur);
    bucket_scatter<<<(N_EDGES + CH - 1) / CH, 256, 0, stream>>>(src, dst, bcur, pairs);
    csr_fill_bucket<<<NB, 256, 0, stream>>>(pairs, boffs, rinfo, dinv, srcs);

    // ---- weight conversion ----
    convert_w<<<(128 * 128 + 64 * 128 + 255) / 256, 256, 0, stream>>>(W1, W2, w1h, w2h);

    // ---- layer 1 ----
    gemm1_mfma<<<MROWS / 128, 512, 0, stream>>>(x, w1h, dinv, y1f);
    agg_relu<<<N_NODES / 8, 256, 0, stream>>>(rinfo, srcs, y1f, dinv, b1, h1b);

    // ---- layer 2 ----
    gemm2_mfma<<<MROWS / 128, 512, 0, stream>>>(h1b, w2h, dinv, y2f);
    agg_lsm<<<N_NODES / 8, 256, 0, stream>>>(rinfo, srcs, y2f, dinv, b2, out);
}